// Round 1
// baseline (759.067 us; speedup 1.0000x reference)
//
#include <hip/hip_runtime.h>

#define N_NODES 50000
#define N_EDGES 800000
#define IN_CH 128
#define HID 64
#define OUT_CH 40

// ---------------------------------------------------------------------------
// ws layout (floats):
//   counts : [N]          edge in-degree per dst node
//   sum1   : [N*IN_CH]    sum of x[src] per dst
//   h1     : [N*HID]      layer-1 output (post-ReLU)
//   sum2   : [N*HID]      sum of h1[src] per dst
// ---------------------------------------------------------------------------

__global__ __launch_bounds__(256) void scatter1_kernel(
    const float* __restrict__ x, const int* __restrict__ src,
    const int* __restrict__ dst, float* __restrict__ sum1,
    float* __restrict__ counts) {
  int e = blockIdx.x * 2 + threadIdx.y;
  if (e >= N_EDGES) return;
  int s = src[e];
  int d = dst[e];
  int c = threadIdx.x;  // 0..127
  atomicAdd(&sum1[(size_t)d * IN_CH + c], x[(size_t)s * IN_CH + c]);
  if (c == 0) atomicAdd(&counts[d], 1.0f);
}

__global__ __launch_bounds__(256) void scatter2_kernel(
    const float* __restrict__ h1, const int* __restrict__ src,
    const int* __restrict__ dst, float* __restrict__ sum2) {
  int e = blockIdx.x * 4 + threadIdx.y;
  if (e >= N_EDGES) return;
  int s = src[e];
  int d = dst[e];
  int c = threadIdx.x;  // 0..63
  atomicAdd(&sum2[(size_t)d * HID + c], h1[(size_t)s * HID + c]);
}

// h1[n,h] = relu( mean1[n,:] . W1l[h,:] + b1[h] + x[n,:] . W1r[h,:] )
__global__ __launch_bounds__(256) void layer1_kernel(
    const float* __restrict__ x, const float* __restrict__ sum1,
    const float* __restrict__ counts, const float* __restrict__ Wl,
    const float* __restrict__ b, const float* __restrict__ Wr,
    float* __restrict__ h1) {
  // W stored transposed [c][h] with +1 pad -> sW[c][lane] reads hit all banks
  __shared__ float sWl[IN_CH][HID + 1];
  __shared__ float sWr[IN_CH][HID + 1];
  for (int i = threadIdx.x; i < HID * IN_CH; i += 256) {
    int h = i >> 7;          // row of W [HID, IN_CH]
    int c = i & (IN_CH - 1); // col
    sWl[c][h] = Wl[i];
    sWr[c][h] = Wr[i];
  }
  __syncthreads();

  int wave = threadIdx.x >> 6;
  int lane = threadIdx.x & 63;
  float bias = b[lane];  // HID == 64, one output per lane
  int n0 = blockIdx.x * 32 + wave * 8;
  for (int i = 0; i < 8; ++i) {
    int n = n0 + i;
    if (n >= N_NODES) return;
    float inv = 1.0f / fmaxf(counts[n], 1.0f);
    const float* xr = x + (size_t)n * IN_CH;
    const float* sr = sum1 + (size_t)n * IN_CH;
    float accl = 0.f, accr = 0.f;
#pragma unroll 16
    for (int c = 0; c < IN_CH; ++c) {
      accl = fmaf(sr[c] * inv, sWl[c][lane], accl);  // mean branch
      accr = fmaf(xr[c], sWr[c][lane], accr);        // self branch
    }
    float v = accl + bias + accr;
    h1[(size_t)n * HID + lane] = fmaxf(v, 0.f);
  }
}

// out[n,o] = log_softmax( mean2[n,:] . W2l[o,:] + b2[o] + h1[n,:] . W2r[o,:] )
__global__ __launch_bounds__(256) void layer2_kernel(
    const float* __restrict__ h1, const float* __restrict__ sum2,
    const float* __restrict__ counts, const float* __restrict__ Wl,
    const float* __restrict__ b, const float* __restrict__ Wr,
    float* __restrict__ out) {
  __shared__ float sWl[HID][OUT_CH + 1];
  __shared__ float sWr[HID][OUT_CH + 1];
  for (int i = threadIdx.x; i < OUT_CH * HID; i += 256) {
    int o = i >> 6;         // row of W [OUT_CH, HID]
    int c = i & (HID - 1);  // col
    sWl[c][o] = Wl[i];
    sWr[c][o] = Wr[i];
  }
  __syncthreads();

  int wave = threadIdx.x >> 6;
  int lane = threadIdx.x & 63;
  int n = blockIdx.x * 4 + wave;
  if (n >= N_NODES) return;

  float inv = 1.0f / fmaxf(counts[n], 1.0f);
  const float* hr = h1 + (size_t)n * HID;
  const float* sr = sum2 + (size_t)n * HID;

  float logit = -1e30f;
  if (lane < OUT_CH) {
    float accl = 0.f, accr = 0.f;
#pragma unroll
    for (int c = 0; c < HID; ++c) {
      accl = fmaf(sr[c] * inv, sWl[c][lane], accl);
      accr = fmaf(hr[c], sWr[c][lane], accr);
    }
    logit = accl + b[lane] + accr;
  }

  // log_softmax across the 40 valid lanes (64-lane butterfly; idle lanes are
  // -1e30 for max / 0 for sum so they are identity elements)
  float m = logit;
  for (int off = 32; off; off >>= 1) m = fmaxf(m, __shfl_xor(m, off));
  float e = (lane < OUT_CH) ? expf(logit - m) : 0.f;
  float ssum = e;
  for (int off = 32; off; off >>= 1) ssum += __shfl_xor(ssum, off);
  float lse = logf(ssum);
  if (lane < OUT_CH) out[(size_t)n * OUT_CH + lane] = logit - m - lse;
}

extern "C" void kernel_launch(void* const* d_in, const int* in_sizes, int n_in,
                              void* d_out, int out_size, void* d_ws, size_t ws_size,
                              hipStream_t stream) {
  const float* x   = (const float*)d_in[0];
  const int*   ei  = (const int*)d_in[1];
  const float* W1l = (const float*)d_in[2];
  const float* b1  = (const float*)d_in[3];
  const float* W1r = (const float*)d_in[4];
  const float* W2l = (const float*)d_in[5];
  const float* b2  = (const float*)d_in[6];
  const float* W2r = (const float*)d_in[7];
  float* out = (float*)d_out;

  float* counts = (float*)d_ws;                      // [N]
  float* sum1   = counts + N_NODES;                  // [N*IN_CH]
  float* h1     = sum1 + (size_t)N_NODES * IN_CH;    // [N*HID]
  float* sum2   = h1 + (size_t)N_NODES * HID;        // [N*HID]

  const int* src = ei;            // edge_index[0]
  const int* dst = ei + N_EDGES;  // edge_index[1]

  // zero accumulators (counts+sum1 contiguous)
  hipMemsetAsync(counts, 0,
                 sizeof(float) * (N_NODES + (size_t)N_NODES * IN_CH), stream);
  hipMemsetAsync(sum2, 0, sizeof(float) * (size_t)N_NODES * HID, stream);

  scatter1_kernel<<<(N_EDGES + 1) / 2, dim3(128, 2), 0, stream>>>(
      x, src, dst, sum1, counts);
  layer1_kernel<<<(N_NODES + 31) / 32, 256, 0, stream>>>(
      x, sum1, counts, W1l, b1, W1r, h1);
  scatter2_kernel<<<(N_EDGES + 3) / 4, dim3(64, 4), 0, stream>>>(
      h1, src, dst, sum2);
  layer2_kernel<<<(N_NODES + 3) / 4, 256, 0, stream>>>(
      h1, sum2, counts, W2l, b2, W2r, out);
}

// Round 3
// 580.970 us; speedup vs baseline: 1.3066x; 1.3066x over previous
//
#include <hip/hip_runtime.h>

#define N_NODES 50000
#define N_EDGES 800000
#define IN_CH 128
#define HID 64
#define OUT_CH 40
#define NB_SCAN 196  // ceil(50000/256)

// ---------------------------------------------------------------------------
// Strategy: no fp atomics. Build CSR (dst-sorted edge list) with int atomics,
// then gather-aggregate. Transform rows BEFORE aggregating so the gathered
// rows are the small post-GEMM width (64 then 40 ch) instead of 128.
//   layer1: h1 = relu( mean_gather(xW1l) + x@W1r.T + b1 )
//   layer2: out = log_softmax( mean_gather(h1W2l) + h1@W2r.T + b2 )
//
// ws layout:
//   xwl  f[N*HID]     x @ W1l.T
//   h1   f[N*HID]     layer-1 output
//   hw2  f[N*OUT_CH]  h1 @ W2l.T
//   cnt  i[N]         in-degree histogram
//   off  i[N]         CSR row offsets (exclusive scan of cnt)
//   cur  i[N]         placement cursors
//   bsum i[256]       scan block sums
//   csr  i[E]         src node id per CSR slot
// ---------------------------------------------------------------------------

__global__ __launch_bounds__(256) void hist_kernel(const int* __restrict__ dst,
                                                   int* __restrict__ cnt) {
  int e = blockIdx.x * 256 + threadIdx.x;
  if (e < N_EDGES) atomicAdd(&cnt[dst[e]], 1);
}

__global__ __launch_bounds__(256) void scan1_kernel(const int* __restrict__ cnt,
                                                    int* __restrict__ off,
                                                    int* __restrict__ bsum) {
  __shared__ int s[256];
  int i = blockIdx.x * 256 + threadIdx.x;
  int v = (i < N_NODES) ? cnt[i] : 0;
  s[threadIdx.x] = v;
  __syncthreads();
  for (int o = 1; o < 256; o <<= 1) {
    int t = (threadIdx.x >= o) ? s[threadIdx.x - o] : 0;
    __syncthreads();
    s[threadIdx.x] += t;
    __syncthreads();
  }
  if (i < N_NODES) off[i] = s[threadIdx.x] - v;  // exclusive within block
  if (threadIdx.x == 255) bsum[blockIdx.x] = s[255];
}

__global__ __launch_bounds__(256) void scan2_kernel(int* __restrict__ bsum) {
  __shared__ int s[256];
  int v = (threadIdx.x < NB_SCAN) ? bsum[threadIdx.x] : 0;
  s[threadIdx.x] = v;
  __syncthreads();
  for (int o = 1; o < 256; o <<= 1) {
    int t = (threadIdx.x >= o) ? s[threadIdx.x - o] : 0;
    __syncthreads();
    s[threadIdx.x] += t;
    __syncthreads();
  }
  if (threadIdx.x < NB_SCAN) bsum[threadIdx.x] = s[threadIdx.x] - v;  // exclusive
}

__global__ __launch_bounds__(256) void scan3_kernel(int* __restrict__ off,
                                                    const int* __restrict__ bsum,
                                                    int* __restrict__ cur) {
  int i = blockIdx.x * 256 + threadIdx.x;
  if (i < N_NODES) {
    int o = off[i] + bsum[blockIdx.x];
    off[i] = o;
    cur[i] = o;
  }
}

__global__ __launch_bounds__(256) void place_kernel(const int* __restrict__ src,
                                                    const int* __restrict__ dst,
                                                    int* __restrict__ cur,
                                                    int* __restrict__ csr) {
  int e = blockIdx.x * 256 + threadIdx.x;
  if (e < N_EDGES) {
    int pos = atomicAdd(&cur[dst[e]], 1);
    csr[pos] = src[e];
  }
}

// xwl[n,h] = x[n,:] . W1l[h,:]
__global__ __launch_bounds__(256) void xw1_kernel(const float* __restrict__ x,
                                                  const float* __restrict__ Wl,
                                                  float* __restrict__ xwl) {
  __shared__ float sW[IN_CH][HID + 1];
  for (int i = threadIdx.x; i < HID * IN_CH; i += 256) {
    int h = i >> 7, c = i & (IN_CH - 1);
    sW[c][h] = Wl[i];
  }
  __syncthreads();
  int wave = threadIdx.x >> 6, lane = threadIdx.x & 63;
  int n0 = blockIdx.x * 32 + wave * 8;
  for (int i = 0; i < 8; ++i) {
    int n = n0 + i;
    if (n >= N_NODES) return;
    const float* xr = x + (size_t)n * IN_CH;
    float acc = 0.f;
#pragma unroll 16
    for (int c = 0; c < IN_CH; ++c) acc = fmaf(xr[c], sW[c][lane], acc);
    xwl[(size_t)n * HID + lane] = acc;
  }
}

// h1[n,h] = relu( gather_mean(xwl)[n,h] + x[n,:].W1r[h,:] + b1[h] )
__global__ __launch_bounds__(256) void agg1_kernel(
    const float* __restrict__ x, const float* __restrict__ xwl,
    const float* __restrict__ Wr, const float* __restrict__ b1,
    const int* __restrict__ cnt, const int* __restrict__ off,
    const int* __restrict__ csr, float* __restrict__ h1) {
  __shared__ float sW[IN_CH][HID + 1];
  for (int i = threadIdx.x; i < HID * IN_CH; i += 256) {
    int h = i >> 7, c = i & (IN_CH - 1);
    sW[c][h] = Wr[i];
  }
  __syncthreads();
  int wave = threadIdx.x >> 6, lane = threadIdx.x & 63;
  float bias = b1[lane];
  int n0 = blockIdx.x * 16 + wave * 4;
  for (int i = 0; i < 4; ++i) {
    int n = n0 + i;
    if (n >= N_NODES) return;
    const float* xr = x + (size_t)n * IN_CH;
    float self = bias;
#pragma unroll 16
    for (int c = 0; c < IN_CH; ++c) self = fmaf(xr[c], sW[c][lane], self);
    int deg = cnt[n], base = off[n];
    float acc = 0.f;
    for (int k = 0; k < deg; ++k) {
      int s = csr[base + k];
      acc += xwl[(size_t)s * HID + lane];
    }
    float inv = 1.0f / fmaxf((float)deg, 1.0f);
    h1[(size_t)n * HID + lane] = fmaxf(acc * inv + self, 0.f);
  }
}

// hw2[n,o] = h1[n,:] . W2l[o,:]
__global__ __launch_bounds__(256) void xw2_kernel(const float* __restrict__ h1,
                                                  const float* __restrict__ Wl,
                                                  float* __restrict__ hw2) {
  __shared__ float sW[HID][OUT_CH + 1];
  for (int i = threadIdx.x; i < OUT_CH * HID; i += 256) {
    int o = i >> 6, c = i & (HID - 1);
    sW[c][o] = Wl[i];
  }
  __syncthreads();
  int wave = threadIdx.x >> 6, lane = threadIdx.x & 63;
  int n0 = blockIdx.x * 16 + wave * 4;
  for (int i = 0; i < 4; ++i) {
    int n = n0 + i;
    if (n >= N_NODES) return;
    if (lane < OUT_CH) {
      const float* hr = h1 + (size_t)n * HID;
      float acc = 0.f;
#pragma unroll
      for (int c = 0; c < HID; ++c) acc = fmaf(hr[c], sW[c][lane], acc);
      hw2[(size_t)n * OUT_CH + lane] = acc;
    }
  }
}

// out[n,o] = log_softmax( gather_mean(hw2)[n,o] + h1[n,:].W2r[o,:] + b2[o] )
__global__ __launch_bounds__(256) void agg2_kernel(
    const float* __restrict__ h1, const float* __restrict__ hw2,
    const float* __restrict__ Wr, const float* __restrict__ b2,
    const int* __restrict__ cnt, const int* __restrict__ off,
    const int* __restrict__ csr, float* __restrict__ out) {
  __shared__ float sW[HID][OUT_CH + 1];
  for (int i = threadIdx.x; i < OUT_CH * HID; i += 256) {
    int o = i >> 6, c = i & (HID - 1);
    sW[c][o] = Wr[i];
  }
  __syncthreads();
  int wave = threadIdx.x >> 6, lane = threadIdx.x & 63;
  int n0 = blockIdx.x * 16 + wave * 4;
  for (int i = 0; i < 4; ++i) {
    int n = n0 + i;
    if (n >= N_NODES) return;
    int deg = cnt[n], base = off[n];
    float inv = 1.0f / fmaxf((float)deg, 1.0f);
    float logit = -1e30f;
    if (lane < OUT_CH) {
      const float* hr = h1 + (size_t)n * HID;
      float self = b2[lane];
#pragma unroll
      for (int c = 0; c < HID; ++c) self = fmaf(hr[c], sW[c][lane], self);
      float acc = 0.f;
      for (int k = 0; k < deg; ++k) {
        int s = csr[base + k];
        acc += hw2[(size_t)s * OUT_CH + lane];
      }
      logit = acc * inv + self;
    }
    // log_softmax over 40 valid lanes (idle lanes carry identity elements)
    float m = logit;
    for (int o = 32; o; o >>= 1) m = fmaxf(m, __shfl_xor(m, o));
    float e = (lane < OUT_CH) ? expf(logit - m) : 0.f;
    float ssum = e;
    for (int o = 32; o; o >>= 1) ssum += __shfl_xor(ssum, o);
    float lse = logf(ssum);
    if (lane < OUT_CH) out[(size_t)n * OUT_CH + lane] = logit - m - lse;
  }
}

extern "C" void kernel_launch(void* const* d_in, const int* in_sizes, int n_in,
                              void* d_out, int out_size, void* d_ws, size_t ws_size,
                              hipStream_t stream) {
  const float* x   = (const float*)d_in[0];
  const int*   ei  = (const int*)d_in[1];
  const float* W1l = (const float*)d_in[2];
  const float* b1  = (const float*)d_in[3];
  const float* W1r = (const float*)d_in[4];
  const float* W2l = (const float*)d_in[5];
  const float* b2  = (const float*)d_in[6];
  const float* W2r = (const float*)d_in[7];
  float* out = (float*)d_out;

  const int* src = ei;            // edge_index[0]
  const int* dst = ei + N_EDGES;  // edge_index[1]

  // ws layout
  float* xwl = (float*)d_ws;                         // [N*HID]
  float* h1  = xwl + (size_t)N_NODES * HID;          // [N*HID]
  float* hw2 = h1 + (size_t)N_NODES * HID;           // [N*OUT_CH]
  int* cnt  = (int*)(hw2 + (size_t)N_NODES * OUT_CH);  // [N]
  int* off  = cnt + N_NODES;                         // [N]
  int* cur  = off + N_NODES;                         // [N]
  int* bsum = cur + N_NODES;                         // [256]
  int* csr  = bsum + 256;                            // [E]

  hipMemsetAsync(cnt, 0, sizeof(int) * N_NODES, stream);

  const int EB = (N_EDGES + 255) / 256;  // 3125
  hist_kernel<<<EB, 256, 0, stream>>>(dst, cnt);
  scan1_kernel<<<NB_SCAN, 256, 0, stream>>>(cnt, off, bsum);
  scan2_kernel<<<1, 256, 0, stream>>>(bsum);
  scan3_kernel<<<NB_SCAN, 256, 0, stream>>>(off, bsum, cur);
  place_kernel<<<EB, 256, 0, stream>>>(src, dst, cur, csr);

  xw1_kernel<<<(N_NODES + 31) / 32, 256, 0, stream>>>(x, W1l, xwl);
  agg1_kernel<<<(N_NODES + 15) / 16, 256, 0, stream>>>(x, xwl, W1r, b1, cnt, off,
                                                       csr, h1);
  xw2_kernel<<<(N_NODES + 15) / 16, 256, 0, stream>>>(h1, W2l, hw2);
  agg2_kernel<<<(N_NODES + 15) / 16, 256, 0, stream>>>(h1, hw2, W2r, b2, cnt, off,
                                                       csr, out);
}

// Round 4
// 354.770 us; speedup vs baseline: 2.1396x; 1.6376x over previous
//
#include <hip/hip_runtime.h>

#define N_NODES 50000
#define N_EDGES 800000
#define IN_CH 128
#define HID 64
#define OUT_CH 40
#define NB_SCAN 196  // ceil(50000/256)

// ---------------------------------------------------------------------------
// CSR gather, no fp atomics. Transform-before-aggregate:
//   layer1: h1 = relu( gather_mean(x@W1l.T) + x@W1r.T + b1 );  hw2 = h1@W2l.T
//   layer2: out = log_softmax( gather_mean(hw2) + h1@W2r.T + b2 )
// Gather tables (xwl, hw2) stored bf16 so they (nearly) fit per-XCD L2 and
// gather bytes halve. Gather loop is 8-wide unrolled (8 independent index
// loads + 8 independent row loads in flight) with a masked 8-wide remainder.
//
// ws layout:
//   h1   f32[N*HID], xwl bf16[N*HID], hw2 bf16[N*OUT_CH],
//   cnt/off/cur i32[N], bsum i32[256], csr i32[E]
// ---------------------------------------------------------------------------

__device__ __forceinline__ ushort f2bf(float f) {
  unsigned u = __float_as_uint(f);
  return (ushort)((u + 0x7FFF + ((u >> 16) & 1)) >> 16);  // RNE
}
__device__ __forceinline__ float bf2f(ushort u) {
  return __uint_as_float(((unsigned)u) << 16);
}

__global__ __launch_bounds__(256) void hist_kernel(const int* __restrict__ dst,
                                                   int* __restrict__ cnt) {
  int e = blockIdx.x * 256 + threadIdx.x;
  if (e < N_EDGES) atomicAdd(&cnt[dst[e]], 1);
}

__global__ __launch_bounds__(256) void scan1_kernel(const int* __restrict__ cnt,
                                                    int* __restrict__ off,
                                                    int* __restrict__ bsum) {
  __shared__ int s[256];
  int i = blockIdx.x * 256 + threadIdx.x;
  int v = (i < N_NODES) ? cnt[i] : 0;
  s[threadIdx.x] = v;
  __syncthreads();
  for (int o = 1; o < 256; o <<= 1) {
    int t = (threadIdx.x >= o) ? s[threadIdx.x - o] : 0;
    __syncthreads();
    s[threadIdx.x] += t;
    __syncthreads();
  }
  if (i < N_NODES) off[i] = s[threadIdx.x] - v;
  if (threadIdx.x == 255) bsum[blockIdx.x] = s[255];
}

__global__ __launch_bounds__(256) void scan2_kernel(int* __restrict__ bsum) {
  __shared__ int s[256];
  int v = (threadIdx.x < NB_SCAN) ? bsum[threadIdx.x] : 0;
  s[threadIdx.x] = v;
  __syncthreads();
  for (int o = 1; o < 256; o <<= 1) {
    int t = (threadIdx.x >= o) ? s[threadIdx.x - o] : 0;
    __syncthreads();
    s[threadIdx.x] += t;
    __syncthreads();
  }
  if (threadIdx.x < NB_SCAN) bsum[threadIdx.x] = s[threadIdx.x] - v;
}

__global__ __launch_bounds__(256) void scan3_kernel(int* __restrict__ off,
                                                    const int* __restrict__ bsum,
                                                    int* __restrict__ cur) {
  int i = blockIdx.x * 256 + threadIdx.x;
  if (i < N_NODES) {
    int o = off[i] + bsum[blockIdx.x];
    off[i] = o;
    cur[i] = o;
  }
}

__global__ __launch_bounds__(256) void place_kernel(const int* __restrict__ src,
                                                    const int* __restrict__ dst,
                                                    int* __restrict__ cur,
                                                    int* __restrict__ csr) {
  int e = blockIdx.x * 256 + threadIdx.x;
  if (e < N_EDGES) {
    int pos = atomicAdd(&cur[dst[e]], 1);
    csr[pos] = src[e];
  }
}

// xwl[n,h] = bf16( x[n,:] . W1l[h,:] )
__global__ __launch_bounds__(256) void xw1_kernel(const float* __restrict__ x,
                                                  const float* __restrict__ Wl,
                                                  ushort* __restrict__ xwl) {
  __shared__ float sW[IN_CH][HID + 1];
  for (int i = threadIdx.x; i < HID * IN_CH; i += 256) {
    int h = i >> 7, c = i & (IN_CH - 1);
    sW[c][h] = Wl[i];
  }
  __syncthreads();
  int wave = threadIdx.x >> 6, lane = threadIdx.x & 63;
  int n0 = blockIdx.x * 32 + wave * 8;
  for (int i = 0; i < 8; ++i) {
    int n = n0 + i;
    if (n >= N_NODES) return;
    const float* xr = x + (size_t)n * IN_CH;
    float acc = 0.f;
#pragma unroll 16
    for (int c = 0; c < IN_CH; ++c) acc = fmaf(xr[c], sW[c][lane], acc);
    xwl[(size_t)n * HID + lane] = f2bf(acc);
  }
}

// h1[n,h] = relu( gather_mean(xwl) + x[n,:].W1r[h,:] + b1[h] )
// hw2[n,o] = bf16( h1[n,:] . W2l[o,:] )   (fused; wave-local LDS staging)
__global__ __launch_bounds__(256) void agg1_kernel(
    const float* __restrict__ x, const ushort* __restrict__ xwl,
    const float* __restrict__ W1r, const float* __restrict__ b1,
    const float* __restrict__ W2l, const int* __restrict__ cnt,
    const int* __restrict__ off, const int* __restrict__ csr,
    float* __restrict__ h1, ushort* __restrict__ hw2) {
  __shared__ float sWr[IN_CH][HID + 1];   // 33280 B
  __shared__ float sW2[HID][OUT_CH + 1];  // 10496 B
  __shared__ float sh1[4][HID];           // 1024 B
  for (int i = threadIdx.x; i < HID * IN_CH; i += 256) {
    int h = i >> 7, c = i & (IN_CH - 1);
    sWr[c][h] = W1r[i];
  }
  for (int i = threadIdx.x; i < OUT_CH * HID; i += 256) {
    int o = i >> 6, c = i & (HID - 1);
    sW2[c][o] = W2l[i];
  }
  __syncthreads();
  int wave = threadIdx.x >> 6, lane = threadIdx.x & 63;
  int n = blockIdx.x * 4 + wave;
  if (n >= N_NODES) return;

  int deg = cnt[n], base = off[n];
  // --- gather: 8-wide MLP ---
  float acc = 0.f;
  int k = 0;
  for (; k + 8 <= deg; k += 8) {
    int s0 = csr[base + k + 0], s1 = csr[base + k + 1];
    int s2 = csr[base + k + 2], s3 = csr[base + k + 3];
    int s4 = csr[base + k + 4], s5 = csr[base + k + 5];
    int s6 = csr[base + k + 6], s7 = csr[base + k + 7];
    float v0 = bf2f(xwl[(size_t)s0 * HID + lane]);
    float v1 = bf2f(xwl[(size_t)s1 * HID + lane]);
    float v2 = bf2f(xwl[(size_t)s2 * HID + lane]);
    float v3 = bf2f(xwl[(size_t)s3 * HID + lane]);
    float v4 = bf2f(xwl[(size_t)s4 * HID + lane]);
    float v5 = bf2f(xwl[(size_t)s5 * HID + lane]);
    float v6 = bf2f(xwl[(size_t)s6 * HID + lane]);
    float v7 = bf2f(xwl[(size_t)s7 * HID + lane]);
    acc += ((v0 + v1) + (v2 + v3)) + ((v4 + v5) + (v6 + v7));
  }
  if (k < deg) {  // masked 8-wide remainder (no serial tail)
#pragma unroll
    for (int i = 0; i < 8; ++i) {
      int kk = k + i;
      int s_ = csr[base + (kk < deg ? kk : k)];
      float v = bf2f(xwl[(size_t)s_ * HID + lane]);
      if (kk < deg) acc += v;
    }
  }
  // --- self path ---
  const float* xr = x + (size_t)n * IN_CH;
  float self = b1[lane];
#pragma unroll 16
  for (int c = 0; c < IN_CH; ++c) self = fmaf(xr[c], sWr[c][lane], self);

  float inv = 1.0f / fmaxf((float)deg, 1.0f);
  float h = fmaxf(acc * inv + self, 0.f);
  h1[(size_t)n * HID + lane] = h;

  // --- fused hw2 = h1 . W2l.T (wave-coherent LDS, no barrier needed) ---
  sh1[wave][lane] = h;
  if (lane < OUT_CH) {
    float o2 = 0.f;
#pragma unroll 16
    for (int c = 0; c < HID; ++c) o2 = fmaf(sh1[wave][c], sW2[c][lane], o2);
    hw2[(size_t)n * OUT_CH + lane] = f2bf(o2);
  }
}

// out[n,o] = log_softmax( gather_mean(hw2) + h1[n,:].W2r[o,:] + b2[o] )
__global__ __launch_bounds__(256) void agg2_kernel(
    const float* __restrict__ h1, const ushort* __restrict__ hw2,
    const float* __restrict__ W2r, const float* __restrict__ b2,
    const int* __restrict__ cnt, const int* __restrict__ off,
    const int* __restrict__ csr, float* __restrict__ out) {
  __shared__ float sW[HID][OUT_CH + 1];
  for (int i = threadIdx.x; i < OUT_CH * HID; i += 256) {
    int o = i >> 6, c = i & (HID - 1);
    sW[c][o] = W2r[i];
  }
  __syncthreads();
  int wave = threadIdx.x >> 6, lane = threadIdx.x & 63;
  int n = blockIdx.x * 4 + wave;
  if (n >= N_NODES) return;

  int deg = cnt[n], base = off[n];
  float logit = -1e30f;
  if (lane < OUT_CH) {
    float acc = 0.f;
    int k = 0;
    for (; k + 8 <= deg; k += 8) {
      int s0 = csr[base + k + 0], s1 = csr[base + k + 1];
      int s2 = csr[base + k + 2], s3 = csr[base + k + 3];
      int s4 = csr[base + k + 4], s5 = csr[base + k + 5];
      int s6 = csr[base + k + 6], s7 = csr[base + k + 7];
      float v0 = bf2f(hw2[(size_t)s0 * OUT_CH + lane]);
      float v1 = bf2f(hw2[(size_t)s1 * OUT_CH + lane]);
      float v2 = bf2f(hw2[(size_t)s2 * OUT_CH + lane]);
      float v3 = bf2f(hw2[(size_t)s3 * OUT_CH + lane]);
      float v4 = bf2f(hw2[(size_t)s4 * OUT_CH + lane]);
      float v5 = bf2f(hw2[(size_t)s5 * OUT_CH + lane]);
      float v6 = bf2f(hw2[(size_t)s6 * OUT_CH + lane]);
      float v7 = bf2f(hw2[(size_t)s7 * OUT_CH + lane]);
      acc += ((v0 + v1) + (v2 + v3)) + ((v4 + v5) + (v6 + v7));
    }
    if (k < deg) {
#pragma unroll
      for (int i = 0; i < 8; ++i) {
        int kk = k + i;
        int s_ = csr[base + (kk < deg ? kk : k)];
        float v = bf2f(hw2[(size_t)s_ * OUT_CH + lane]);
        if (kk < deg) acc += v;
      }
    }
    const float* hr = h1 + (size_t)n * HID;
    float self = b2[lane];
#pragma unroll 16
    for (int c = 0; c < HID; ++c) self = fmaf(hr[c], sW[c][lane], self);
    logit = acc / fmaxf((float)deg, 1.0f) + self;
  }
  // log_softmax over 40 valid lanes (idle lanes carry identity elements)
  float m = logit;
  for (int o = 32; o; o >>= 1) m = fmaxf(m, __shfl_xor(m, o));
  float e = (lane < OUT_CH) ? expf(logit - m) : 0.f;
  float ssum = e;
  for (int o = 32; o; o >>= 1) ssum += __shfl_xor(ssum, o);
  float lse = logf(ssum);
  if (lane < OUT_CH) out[(size_t)n * OUT_CH + lane] = logit - m - lse;
}

extern "C" void kernel_launch(void* const* d_in, const int* in_sizes, int n_in,
                              void* d_out, int out_size, void* d_ws, size_t ws_size,
                              hipStream_t stream) {
  const float* x   = (const float*)d_in[0];
  const int*   ei  = (const int*)d_in[1];
  const float* W1l = (const float*)d_in[2];
  const float* b1  = (const float*)d_in[3];
  const float* W1r = (const float*)d_in[4];
  const float* W2l = (const float*)d_in[5];
  const float* b2  = (const float*)d_in[6];
  const float* W2r = (const float*)d_in[7];
  float* out = (float*)d_out;

  const int* src = ei;            // edge_index[0]
  const int* dst = ei + N_EDGES;  // edge_index[1]

  // ws layout (h1 f32, then bf16 tables, then ints; all 4B-aligned)
  float* h1  = (float*)d_ws;                             // [N*HID] f32
  ushort* xwl = (ushort*)(h1 + (size_t)N_NODES * HID);   // [N*HID] bf16
  ushort* hw2 = xwl + (size_t)N_NODES * HID;             // [N*OUT_CH] bf16
  int* cnt  = (int*)(hw2 + (size_t)N_NODES * OUT_CH);    // [N]
  int* off  = cnt + N_NODES;                             // [N]
  int* cur  = off + N_NODES;                             // [N]
  int* bsum = cur + N_NODES;                             // [256]
  int* csr  = bsum + 256;                                // [E]

  hipMemsetAsync(cnt, 0, sizeof(int) * N_NODES, stream);

  const int EB = (N_EDGES + 255) / 256;  // 3125
  hist_kernel<<<EB, 256, 0, stream>>>(dst, cnt);
  scan1_kernel<<<NB_SCAN, 256, 0, stream>>>(cnt, off, bsum);
  scan2_kernel<<<1, 256, 0, stream>>>(bsum);
  scan3_kernel<<<NB_SCAN, 256, 0, stream>>>(off, bsum, cur);
  place_kernel<<<EB, 256, 0, stream>>>(src, dst, cur, csr);

  xw1_kernel<<<(N_NODES + 31) / 32, 256, 0, stream>>>(x, W1l, xwl);
  agg1_kernel<<<(N_NODES + 3) / 4, 256, 0, stream>>>(x, xwl, W1r, b1, W2l, cnt,
                                                     off, csr, h1, hw2);
  agg2_kernel<<<(N_NODES + 3) / 4, 256, 0, stream>>>(h1, hw2, W2r, b2, cnt, off,
                                                     csr, out);
}

// Round 6
// 277.091 us; speedup vs baseline: 2.7394x; 1.2803x over previous
//
#include <hip/hip_runtime.h>

#define N_NODES 50000
#define N_EDGES 800000
#define IN_CH 128
#define HID 64
#define OUT_CH 40
#define NB_SCAN 196  // ceil(50000/256)

// ---------------------------------------------------------------------------
// CSR gather, no fp atomics, transform-before-aggregate, all projections
// hoisted out of the latency-bound gather kernels:
//   xform1: xwl = bf16(x@W1l.T)            [gather table, 6.4 MB]
//           xwr = x@W1r.T + b1  (f32)      [self path, read once in agg1]
//   agg1:   h   = relu(gather_mean(xwl) + xwr)      (h stays in-wave)
//           hw2 = bf16(h@W2l.T)            [gather table, 4 MB]
//           self2 = h@W2r.T + b2 (f32)
//   agg2:   out = log_softmax(gather_mean(hw2) + self2)   (no LDS, no weights)
// ---------------------------------------------------------------------------

__device__ __forceinline__ ushort f2bf(float f) {
  unsigned u = __float_as_uint(f);
  return (ushort)((u + 0x7FFF + ((u >> 16) & 1)) >> 16);  // RNE
}
__device__ __forceinline__ float bf2f(ushort u) {
  return __uint_as_float(((unsigned)u) << 16);
}

__global__ __launch_bounds__(256) void hist_kernel(const int* __restrict__ dst,
                                                   int* __restrict__ cnt) {
  int e = blockIdx.x * 256 + threadIdx.x;
  if (e < N_EDGES) atomicAdd(&cnt[dst[e]], 1);
}

__global__ __launch_bounds__(256) void scan1_kernel(const int* __restrict__ cnt,
                                                    int* __restrict__ off,
                                                    int* __restrict__ bsum) {
  __shared__ int s[256];
  int i = blockIdx.x * 256 + threadIdx.x;
  int v = (i < N_NODES) ? cnt[i] : 0;
  s[threadIdx.x] = v;
  __syncthreads();
  for (int o = 1; o < 256; o <<= 1) {
    int t = (threadIdx.x >= o) ? s[threadIdx.x - o] : 0;
    __syncthreads();
    s[threadIdx.x] += t;
    __syncthreads();
  }
  if (i < N_NODES) off[i] = s[threadIdx.x] - v;
  if (threadIdx.x == 255) bsum[blockIdx.x] = s[255];
}

__global__ __launch_bounds__(256) void scan2_kernel(int* __restrict__ bsum) {
  __shared__ int s[256];
  int v = (threadIdx.x < NB_SCAN) ? bsum[threadIdx.x] : 0;
  s[threadIdx.x] = v;
  __syncthreads();
  for (int o = 1; o < 256; o <<= 1) {
    int t = (threadIdx.x >= o) ? s[threadIdx.x - o] : 0;
    __syncthreads();
    s[threadIdx.x] += t;
    __syncthreads();
  }
  if (threadIdx.x < NB_SCAN) bsum[threadIdx.x] = s[threadIdx.x] - v;
}

__global__ __launch_bounds__(256) void scan3_kernel(int* __restrict__ off,
                                                    const int* __restrict__ bsum,
                                                    int* __restrict__ cur) {
  int i = blockIdx.x * 256 + threadIdx.x;
  if (i < N_NODES) {
    int o = off[i] + bsum[blockIdx.x];
    off[i] = o;
    cur[i] = o;
  }
}

__global__ __launch_bounds__(256) void place_kernel(const int* __restrict__ src,
                                                    const int* __restrict__ dst,
                                                    int* __restrict__ cur,
                                                    int* __restrict__ csr) {
  int e = blockIdx.x * 256 + threadIdx.x;
  if (e < N_EDGES) {
    int pos = atomicAdd(&cur[dst[e]], 1);
    csr[pos] = src[e];
  }
}

// xwl[n,h] = bf16(x[n,:].W1l[h,:]);  xwr[n,h] = x[n,:].W1r[h,:] + b1[h]
__global__ __launch_bounds__(256) void xform1_kernel(
    const float* __restrict__ x, const float* __restrict__ W1l,
    const float* __restrict__ W1r, const float* __restrict__ b1,
    ushort* __restrict__ xwl, float* __restrict__ xwr) {
  __shared__ float sWl[IN_CH][HID + 1];
  __shared__ float sWr[IN_CH][HID + 1];
  for (int i = threadIdx.x; i < HID * IN_CH; i += 256) {
    int h = i >> 7, c = i & (IN_CH - 1);
    sWl[c][h] = W1l[i];
    sWr[c][h] = W1r[i];
  }
  __syncthreads();
  int wave = threadIdx.x >> 6, lane = threadIdx.x & 63;
  float bias = b1[lane];
  int n0 = blockIdx.x * 32 + wave * 8;
  for (int i = 0; i < 8; ++i) {
    int n = n0 + i;
    if (n >= N_NODES) return;
    const float* xr = x + (size_t)n * IN_CH;
    float accl = 0.f, accr = bias;
#pragma unroll 16
    for (int c = 0; c < IN_CH; ++c) {
      float xv = xr[c];
      accl = fmaf(xv, sWl[c][lane], accl);
      accr = fmaf(xv, sWr[c][lane], accr);
    }
    xwl[(size_t)n * HID + lane] = f2bf(accl);
    xwr[(size_t)n * HID + lane] = accr;
  }
}

// h = relu(gather_mean(xwl) + xwr);  hw2 = bf16(h@W2l.T);  self2 = h@W2r.T+b2
__global__ __launch_bounds__(256) void agg1_kernel(
    const ushort* __restrict__ xwl, const float* __restrict__ xwr,
    const float* __restrict__ W2l, const float* __restrict__ W2r,
    const float* __restrict__ b2, const int* __restrict__ cnt,
    const int* __restrict__ off, const int* __restrict__ csr,
    ushort* __restrict__ hw2, float* __restrict__ self2) {
  __shared__ float sW2l[HID][OUT_CH + 1];  // 10496 B
  __shared__ float sW2r[HID][OUT_CH + 1];  // 10496 B
  __shared__ float sh1[4][HID];            // 1024 B
  for (int i = threadIdx.x; i < OUT_CH * HID; i += 256) {
    int o = i >> 6, c = i & (HID - 1);
    sW2l[c][o] = W2l[i];
    sW2r[c][o] = W2r[i];
  }
  __syncthreads();
  int wave = threadIdx.x >> 6, lane = threadIdx.x & 63;
  int n = blockIdx.x * 4 + wave;
  if (n >= N_NODES) return;

  int deg = cnt[n], base = off[n];
  float acc = 0.f;
  int k = 0;
  for (; k + 8 <= deg; k += 8) {  // 8-wide MLP gather
    int s0 = csr[base + k + 0], s1 = csr[base + k + 1];
    int s2 = csr[base + k + 2], s3 = csr[base + k + 3];
    int s4 = csr[base + k + 4], s5 = csr[base + k + 5];
    int s6 = csr[base + k + 6], s7 = csr[base + k + 7];
    float v0 = bf2f(xwl[(size_t)s0 * HID + lane]);
    float v1 = bf2f(xwl[(size_t)s1 * HID + lane]);
    float v2 = bf2f(xwl[(size_t)s2 * HID + lane]);
    float v3 = bf2f(xwl[(size_t)s3 * HID + lane]);
    float v4 = bf2f(xwl[(size_t)s4 * HID + lane]);
    float v5 = bf2f(xwl[(size_t)s5 * HID + lane]);
    float v6 = bf2f(xwl[(size_t)s6 * HID + lane]);
    float v7 = bf2f(xwl[(size_t)s7 * HID + lane]);
    acc += ((v0 + v1) + (v2 + v3)) + ((v4 + v5) + (v6 + v7));
  }
  if (k < deg) {  // masked 8-wide remainder
#pragma unroll
    for (int i = 0; i < 8; ++i) {
      int kk = k + i;
      int s_ = csr[base + (kk < deg ? kk : k)];
      float v = bf2f(xwl[(size_t)s_ * HID + lane]);
      if (kk < deg) acc += v;
    }
  }
  float inv = 1.0f / fmaxf((float)deg, 1.0f);
  float h = fmaxf(acc * inv + xwr[(size_t)n * HID + lane], 0.f);

  sh1[wave][lane] = h;  // wave-coherent, no barrier needed
  if (lane < OUT_CH) {
    float o2 = 0.f, s2v = b2[lane];
#pragma unroll 16
    for (int c = 0; c < HID; ++c) {
      float hv = sh1[wave][c];
      o2 = fmaf(hv, sW2l[c][lane], o2);
      s2v = fmaf(hv, sW2r[c][lane], s2v);
    }
    hw2[(size_t)n * OUT_CH + lane] = f2bf(o2);
    self2[(size_t)n * OUT_CH + lane] = s2v;
  }
}

// out = log_softmax(gather_mean(hw2) + self2)  — no LDS, no weights
__global__ __launch_bounds__(256) void agg2_kernel(
    const ushort* __restrict__ hw2, const float* __restrict__ self2,
    const int* __restrict__ cnt, const int* __restrict__ off,
    const int* __restrict__ csr, float* __restrict__ out) {
  int wave = threadIdx.x >> 6, lane = threadIdx.x & 63;
  int n = blockIdx.x * 4 + wave;
  if (n >= N_NODES) return;

  int deg = cnt[n], base = off[n];
  float logit = -1e30f;
  if (lane < OUT_CH) {
    float acc = 0.f;
    int k = 0;
    for (; k + 8 <= deg; k += 8) {
      int s0 = csr[base + k + 0], s1 = csr[base + k + 1];
      int s2 = csr[base + k + 2], s3 = csr[base + k + 3];
      int s4 = csr[base + k + 4], s5 = csr[base + k + 5];
      int s6 = csr[base + k + 6], s7 = csr[base + k + 7];
      float v0 = bf2f(hw2[(size_t)s0 * OUT_CH + lane]);
      float v1 = bf2f(hw2[(size_t)s1 * OUT_CH + lane]);
      float v2 = bf2f(hw2[(size_t)s2 * OUT_CH + lane]);
      float v3 = bf2f(hw2[(size_t)s3 * OUT_CH + lane]);
      float v4 = bf2f(hw2[(size_t)s4 * OUT_CH + lane]);
      float v5 = bf2f(hw2[(size_t)s5 * OUT_CH + lane]);
      float v6 = bf2f(hw2[(size_t)s6 * OUT_CH + lane]);
      float v7 = bf2f(hw2[(size_t)s7 * OUT_CH + lane]);
      acc += ((v0 + v1) + (v2 + v3)) + ((v4 + v5) + (v6 + v7));
    }
    if (k < deg) {
#pragma unroll
      for (int i = 0; i < 8; ++i) {
        int kk = k + i;
        int s_ = csr[base + (kk < deg ? kk : k)];
        float v = bf2f(hw2[(size_t)s_ * OUT_CH + lane]);
        if (kk < deg) acc += v;
      }
    }
    logit = acc / fmaxf((float)deg, 1.0f) + self2[(size_t)n * OUT_CH + lane];
  }
  // log_softmax over 40 valid lanes (idle lanes carry identity elements)
  float m = logit;
  for (int o = 32; o; o >>= 1) m = fmaxf(m, __shfl_xor(m, o));
  float e = (lane < OUT_CH) ? expf(logit - m) : 0.f;
  float ssum = e;
  for (int o = 32; o; o >>= 1) ssum += __shfl_xor(ssum, o);
  float lse = logf(ssum);
  if (lane < OUT_CH) out[(size_t)n * OUT_CH + lane] = logit - m - lse;
}

extern "C" void kernel_launch(void* const* d_in, const int* in_sizes, int n_in,
                              void* d_out, int out_size, void* d_ws, size_t ws_size,
                              hipStream_t stream) {
  const float* x   = (const float*)d_in[0];
  const int*   ei  = (const int*)d_in[1];
  const float* W1l = (const float*)d_in[2];
  const float* b1  = (const float*)d_in[3];
  const float* W1r = (const float*)d_in[4];
  const float* W2l = (const float*)d_in[5];
  const float* b2  = (const float*)d_in[6];
  const float* W2r = (const float*)d_in[7];
  float* out = (float*)d_out;

  const int* src = ei;            // edge_index[0]
  const int* dst = ei + N_EDGES;  // edge_index[1]

  // ws layout: f32 arrays first, then bf16, then ints
  float* xwr   = (float*)d_ws;                             // [N*HID] f32
  float* self2 = xwr + (size_t)N_NODES * HID;              // [N*OUT_CH] f32
  ushort* xwl  = (ushort*)(self2 + (size_t)N_NODES * OUT_CH);  // [N*HID] bf16
  ushort* hw2  = xwl + (size_t)N_NODES * HID;              // [N*OUT_CH] bf16
  int* cnt  = (int*)(hw2 + (size_t)N_NODES * OUT_CH);      // [N]
  int* off  = cnt + N_NODES;                               // [N]
  int* cur  = off + N_NODES;                               // [N]
  int* bsum = cur + N_NODES;                               // [256]
  int* csr  = bsum + 256;                                  // [E]

  hipMemsetAsync(cnt, 0, sizeof(int) * N_NODES, stream);

  const int EB = (N_EDGES + 255) / 256;  // 3125
  hist_kernel<<<EB, 256, 0, stream>>>(dst, cnt);
  scan1_kernel<<<NB_SCAN, 256, 0, stream>>>(cnt, off, bsum);
  scan2_kernel<<<1, 256, 0, stream>>>(bsum);
  scan3_kernel<<<NB_SCAN, 256, 0, stream>>>(off, bsum, cur);
  place_kernel<<<EB, 256, 0, stream>>>(src, dst, cur, csr);

  xform1_kernel<<<(N_NODES + 31) / 32, 256, 0, stream>>>(x, W1l, W1r, b1, xwl,
                                                         xwr);
  agg1_kernel<<<(N_NODES + 3) / 4, 256, 0, stream>>>(xwl, xwr, W2l, W2r, b2,
                                                     cnt, off, csr, hw2, self2);
  agg2_kernel<<<(N_NODES + 3) / 4, 256, 0, stream>>>(hw2, self2, cnt, off, csr,
                                                     out);
}

// Round 7
// 250.845 us; speedup vs baseline: 3.0260x; 1.1046x over previous
//
#include <hip/hip_runtime.h>

#define N_NODES 50000
#define N_EDGES 800000
#define IN_CH 128
#define HID 64
#define OUT_CH 40
#define NB_SCAN 196  // ceil(50000/256)

// ---------------------------------------------------------------------------
// CSR gather, no fp atomics, transform-before-aggregate:
//   xform1: xwl = bf16(x@W1l.T), xwr = x@W1r.T + b1
//           (weight-reads hoisted: 8 nodes/wave share each LDS weight read)
//   agg1:   h = relu(gather_mean(xwl) + xwr); hw2 = bf16(h@W2l.T);
//           self2 = h@W2r.T + b2
//   agg2:   out = log_softmax(gather_mean(hw2) + self2)
// ---------------------------------------------------------------------------

__device__ __forceinline__ ushort f2bf(float f) {
  unsigned u = __float_as_uint(f);
  return (ushort)((u + 0x7FFF + ((u >> 16) & 1)) >> 16);  // RNE
}
__device__ __forceinline__ float bf2f(ushort u) {
  return __uint_as_float(((unsigned)u) << 16);
}

__global__ __launch_bounds__(256) void hist_kernel(const int* __restrict__ dst,
                                                   int* __restrict__ cnt) {
  int e = blockIdx.x * 256 + threadIdx.x;
  if (e < N_EDGES) atomicAdd(&cnt[dst[e]], 1);
}

__global__ __launch_bounds__(256) void scan1_kernel(const int* __restrict__ cnt,
                                                    int* __restrict__ off,
                                                    int* __restrict__ bsum) {
  __shared__ int s[256];
  int i = blockIdx.x * 256 + threadIdx.x;
  int v = (i < N_NODES) ? cnt[i] : 0;
  s[threadIdx.x] = v;
  __syncthreads();
  for (int o = 1; o < 256; o <<= 1) {
    int t = (threadIdx.x >= o) ? s[threadIdx.x - o] : 0;
    __syncthreads();
    s[threadIdx.x] += t;
    __syncthreads();
  }
  if (i < N_NODES) off[i] = s[threadIdx.x] - v;
  if (threadIdx.x == 255) bsum[blockIdx.x] = s[255];
}

__global__ __launch_bounds__(256) void scan2_kernel(int* __restrict__ bsum) {
  __shared__ int s[256];
  int v = (threadIdx.x < NB_SCAN) ? bsum[threadIdx.x] : 0;
  s[threadIdx.x] = v;
  __syncthreads();
  for (int o = 1; o < 256; o <<= 1) {
    int t = (threadIdx.x >= o) ? s[threadIdx.x - o] : 0;
    __syncthreads();
    s[threadIdx.x] += t;
    __syncthreads();
  }
  if (threadIdx.x < NB_SCAN) bsum[threadIdx.x] = s[threadIdx.x] - v;
}

__global__ __launch_bounds__(256) void scan3_kernel(int* __restrict__ off,
                                                    const int* __restrict__ bsum,
                                                    int* __restrict__ cur) {
  int i = blockIdx.x * 256 + threadIdx.x;
  if (i < N_NODES) {
    int o = off[i] + bsum[blockIdx.x];
    off[i] = o;
    cur[i] = o;
  }
}

__global__ __launch_bounds__(256) void place_kernel(const int* __restrict__ src,
                                                    const int* __restrict__ dst,
                                                    int* __restrict__ cur,
                                                    int* __restrict__ csr) {
  int e = blockIdx.x * 256 + threadIdx.x;
  if (e < N_EDGES) {
    int pos = atomicAdd(&cur[dst[e]], 1);
    csr[pos] = src[e];
  }
}

// xwl[n,h] = bf16(x[n,:].W1l[h,:]);  xwr[n,h] = x[n,:].W1r[h,:] + b1[h]
// Loop nest inverted: weights read from LDS once per c-quad per wave and
// applied to 8 nodes (LDS reads cut 8x vs per-node reads -> FMA-bound).
__global__ __launch_bounds__(256) void xform1_kernel(
    const float* __restrict__ x, const float* __restrict__ W1l,
    const float* __restrict__ W1r, const float* __restrict__ b1,
    ushort* __restrict__ xwl, float* __restrict__ xwr) {
  __shared__ float sWl[IN_CH][HID + 1];
  __shared__ float sWr[IN_CH][HID + 1];
  for (int i = threadIdx.x; i < HID * IN_CH; i += 256) {
    int h = i >> 7, c = i & (IN_CH - 1);
    sWl[c][h] = W1l[i];
    sWr[c][h] = W1r[i];
  }
  __syncthreads();
  int wave = threadIdx.x >> 6, lane = threadIdx.x & 63;
  int n0 = blockIdx.x * 32 + wave * 8;
  if (n0 >= N_NODES) return;
  float bias = b1[lane];

  if (n0 + 8 <= N_NODES) {
    float accl[8], accr[8];
#pragma unroll
    for (int i = 0; i < 8; ++i) {
      accl[i] = 0.f;
      accr[i] = bias;
    }
    const float* xb = x + (size_t)n0 * IN_CH;
    for (int c = 0; c < IN_CH; c += 4) {
      float wl0 = sWl[c + 0][lane], wl1 = sWl[c + 1][lane];
      float wl2 = sWl[c + 2][lane], wl3 = sWl[c + 3][lane];
      float wr0 = sWr[c + 0][lane], wr1 = sWr[c + 1][lane];
      float wr2 = sWr[c + 2][lane], wr3 = sWr[c + 3][lane];
#pragma unroll
      for (int i = 0; i < 8; ++i) {
        const float4 xv =
            *reinterpret_cast<const float4*>(xb + (size_t)i * IN_CH + c);
        accl[i] = fmaf(xv.x, wl0, accl[i]);
        accr[i] = fmaf(xv.x, wr0, accr[i]);
        accl[i] = fmaf(xv.y, wl1, accl[i]);
        accr[i] = fmaf(xv.y, wr1, accr[i]);
        accl[i] = fmaf(xv.z, wl2, accl[i]);
        accr[i] = fmaf(xv.z, wr2, accr[i]);
        accl[i] = fmaf(xv.w, wl3, accl[i]);
        accr[i] = fmaf(xv.w, wr3, accr[i]);
      }
    }
#pragma unroll
    for (int i = 0; i < 8; ++i) {
      xwl[(size_t)(n0 + i) * HID + lane] = f2bf(accl[i]);
      xwr[(size_t)(n0 + i) * HID + lane] = accr[i];
    }
  } else {  // partial tail block: per-node scalar path
    for (int i = 0; i < 8; ++i) {
      int n = n0 + i;
      if (n >= N_NODES) return;
      const float* xr = x + (size_t)n * IN_CH;
      float al = 0.f, ar = bias;
#pragma unroll 16
      for (int c = 0; c < IN_CH; ++c) {
        float xv = xr[c];
        al = fmaf(xv, sWl[c][lane], al);
        ar = fmaf(xv, sWr[c][lane], ar);
      }
      xwl[(size_t)n * HID + lane] = f2bf(al);
      xwr[(size_t)n * HID + lane] = ar;
    }
  }
}

// h = relu(gather_mean(xwl) + xwr);  hw2 = bf16(h@W2l.T);  self2 = h@W2r.T+b2
__global__ __launch_bounds__(256) void agg1_kernel(
    const ushort* __restrict__ xwl, const float* __restrict__ xwr,
    const float* __restrict__ W2l, const float* __restrict__ W2r,
    const float* __restrict__ b2, const int* __restrict__ cnt,
    const int* __restrict__ off, const int* __restrict__ csr,
    ushort* __restrict__ hw2, float* __restrict__ self2) {
  __shared__ float sW2l[HID][OUT_CH + 1];  // 10496 B
  __shared__ float sW2r[HID][OUT_CH + 1];  // 10496 B
  __shared__ float sh1[4][HID];            // 1024 B
  for (int i = threadIdx.x; i < OUT_CH * HID; i += 256) {
    int o = i >> 6, c = i & (HID - 1);
    sW2l[c][o] = W2l[i];
    sW2r[c][o] = W2r[i];
  }
  __syncthreads();
  int wave = threadIdx.x >> 6, lane = threadIdx.x & 63;
  int n = blockIdx.x * 4 + wave;
  if (n >= N_NODES) return;

  int deg = cnt[n], base = off[n];
  float acc = 0.f;
  int k = 0;
  for (; k + 8 <= deg; k += 8) {  // 8-wide MLP gather
    int s0 = csr[base + k + 0], s1 = csr[base + k + 1];
    int s2 = csr[base + k + 2], s3 = csr[base + k + 3];
    int s4 = csr[base + k + 4], s5 = csr[base + k + 5];
    int s6 = csr[base + k + 6], s7 = csr[base + k + 7];
    float v0 = bf2f(xwl[(size_t)s0 * HID + lane]);
    float v1 = bf2f(xwl[(size_t)s1 * HID + lane]);
    float v2 = bf2f(xwl[(size_t)s2 * HID + lane]);
    float v3 = bf2f(xwl[(size_t)s3 * HID + lane]);
    float v4 = bf2f(xwl[(size_t)s4 * HID + lane]);
    float v5 = bf2f(xwl[(size_t)s5 * HID + lane]);
    float v6 = bf2f(xwl[(size_t)s6 * HID + lane]);
    float v7 = bf2f(xwl[(size_t)s7 * HID + lane]);
    acc += ((v0 + v1) + (v2 + v3)) + ((v4 + v5) + (v6 + v7));
  }
  if (k < deg) {  // masked 8-wide remainder
#pragma unroll
    for (int i = 0; i < 8; ++i) {
      int kk = k + i;
      int s_ = csr[base + (kk < deg ? kk : k)];
      float v = bf2f(xwl[(size_t)s_ * HID + lane]);
      if (kk < deg) acc += v;
    }
  }
  float inv = 1.0f / fmaxf((float)deg, 1.0f);
  float h = fmaxf(acc * inv + xwr[(size_t)n * HID + lane], 0.f);

  sh1[wave][lane] = h;  // wave-coherent, no barrier needed
  if (lane < OUT_CH) {
    float o2 = 0.f, s2v = b2[lane];
#pragma unroll 16
    for (int c = 0; c < HID; ++c) {
      float hv = sh1[wave][c];
      o2 = fmaf(hv, sW2l[c][lane], o2);
      s2v = fmaf(hv, sW2r[c][lane], s2v);
    }
    hw2[(size_t)n * OUT_CH + lane] = f2bf(o2);
    self2[(size_t)n * OUT_CH + lane] = s2v;
  }
}

// out = log_softmax(gather_mean(hw2) + self2)  — no LDS, no weights
__global__ __launch_bounds__(256) void agg2_kernel(
    const ushort* __restrict__ hw2, const float* __restrict__ self2,
    const int* __restrict__ cnt, const int* __restrict__ off,
    const int* __restrict__ csr, float* __restrict__ out) {
  int wave = threadIdx.x >> 6, lane = threadIdx.x & 63;
  int n = blockIdx.x * 4 + wave;
  if (n >= N_NODES) return;

  int deg = cnt[n], base = off[n];
  float logit = -1e30f;
  if (lane < OUT_CH) {
    float acc = 0.f;
    int k = 0;
    for (; k + 8 <= deg; k += 8) {
      int s0 = csr[base + k + 0], s1 = csr[base + k + 1];
      int s2 = csr[base + k + 2], s3 = csr[base + k + 3];
      int s4 = csr[base + k + 4], s5 = csr[base + k + 5];
      int s6 = csr[base + k + 6], s7 = csr[base + k + 7];
      float v0 = bf2f(hw2[(size_t)s0 * OUT_CH + lane]);
      float v1 = bf2f(hw2[(size_t)s1 * OUT_CH + lane]);
      float v2 = bf2f(hw2[(size_t)s2 * OUT_CH + lane]);
      float v3 = bf2f(hw2[(size_t)s3 * OUT_CH + lane]);
      float v4 = bf2f(hw2[(size_t)s4 * OUT_CH + lane]);
      float v5 = bf2f(hw2[(size_t)s5 * OUT_CH + lane]);
      float v6 = bf2f(hw2[(size_t)s6 * OUT_CH + lane]);
      float v7 = bf2f(hw2[(size_t)s7 * OUT_CH + lane]);
      acc += ((v0 + v1) + (v2 + v3)) + ((v4 + v5) + (v6 + v7));
    }
    if (k < deg) {
#pragma unroll
      for (int i = 0; i < 8; ++i) {
        int kk = k + i;
        int s_ = csr[base + (kk < deg ? kk : k)];
        float v = bf2f(hw2[(size_t)s_ * OUT_CH + lane]);
        if (kk < deg) acc += v;
      }
    }
    logit = acc / fmaxf((float)deg, 1.0f) + self2[(size_t)n * OUT_CH + lane];
  }
  // log_softmax over 40 valid lanes (idle lanes carry identity elements)
  float m = logit;
  for (int o = 32; o; o >>= 1) m = fmaxf(m, __shfl_xor(m, o));
  float e = (lane < OUT_CH) ? expf(logit - m) : 0.f;
  float ssum = e;
  for (int o = 32; o; o >>= 1) ssum += __shfl_xor(ssum, o);
  float lse = logf(ssum);
  if (lane < OUT_CH) out[(size_t)n * OUT_CH + lane] = logit - m - lse;
}

extern "C" void kernel_launch(void* const* d_in, const int* in_sizes, int n_in,
                              void* d_out, int out_size, void* d_ws, size_t ws_size,
                              hipStream_t stream) {
  const float* x   = (const float*)d_in[0];
  const int*   ei  = (const int*)d_in[1];
  const float* W1l = (const float*)d_in[2];
  const float* b1  = (const float*)d_in[3];
  const float* W1r = (const float*)d_in[4];
  const float* W2l = (const float*)d_in[5];
  const float* b2  = (const float*)d_in[6];
  const float* W2r = (const float*)d_in[7];
  float* out = (float*)d_out;

  const int* src = ei;            // edge_index[0]
  const int* dst = ei + N_EDGES;  // edge_index[1]

  // ws layout: f32 arrays first, then bf16, then ints
  float* xwr   = (float*)d_ws;                             // [N*HID] f32
  float* self2 = xwr + (size_t)N_NODES * HID;              // [N*OUT_CH] f32
  ushort* xwl  = (ushort*)(self2 + (size_t)N_NODES * OUT_CH);  // [N*HID] bf16
  ushort* hw2  = xwl + (size_t)N_NODES * HID;              // [N*OUT_CH] bf16
  int* cnt  = (int*)(hw2 + (size_t)N_NODES * OUT_CH);      // [N]
  int* off  = cnt + N_NODES;                               // [N]
  int* cur  = off + N_NODES;                               // [N]
  int* bsum = cur + N_NODES;                               // [256]
  int* csr  = bsum + 256;                                  // [E]

  hipMemsetAsync(cnt, 0, sizeof(int) * N_NODES, stream);

  const int EB = (N_EDGES + 255) / 256;  // 3125
  hist_kernel<<<EB, 256, 0, stream>>>(dst, cnt);
  scan1_kernel<<<NB_SCAN, 256, 0, stream>>>(cnt, off, bsum);
  scan2_kernel<<<1, 256, 0, stream>>>(bsum);
  scan3_kernel<<<NB_SCAN, 256, 0, stream>>>(off, bsum, cur);
  place_kernel<<<EB, 256, 0, stream>>>(src, dst, cur, csr);

  xform1_kernel<<<(N_NODES + 31) / 32, 256, 0, stream>>>(x, W1l, W1r, b1, xwl,
                                                         xwr);
  agg1_kernel<<<(N_NODES + 3) / 4, 256, 0, stream>>>(xwl, xwr, W2l, W2r, b2,
                                                     cnt, off, csr, hw2, self2);
  agg2_kernel<<<(N_NODES + 3) / 4, 256, 0, stream>>>(hw2, self2, cnt, off, csr,
                                                     out);
}

// Round 8
// 249.058 us; speedup vs baseline: 3.0478x; 1.0072x over previous
//
#include <hip/hip_runtime.h>

#define N_NODES 50000
#define N_EDGES 800000
#define IN_CH 128
#define HID 64
#define OUT_CH 40
#define NB_SCAN 196  // ceil(50000/256)

// ---------------------------------------------------------------------------
// CSR gather, no fp atomics, transform-before-aggregate:
//   xform1: xwl = bf16(x@W1l.T), xwr = x@W1r.T + b1
//           (weights staged in LDS as bf16 -> 33 KB -> 4 blocks/CU;
//            weight-reads hoisted: 8 nodes/wave share each LDS read)
//   agg1:   h = relu(gather_mean(xwl) + xwr); hw2 = bf16(h@W2l.T);
//           self2 = h@W2r.T + b2
//   agg2:   out = log_softmax(gather_mean(hw2) + self2)
// ---------------------------------------------------------------------------

__device__ __forceinline__ ushort f2bf(float f) {
  unsigned u = __float_as_uint(f);
  return (ushort)((u + 0x7FFF + ((u >> 16) & 1)) >> 16);  // RNE
}
__device__ __forceinline__ float bf2f(ushort u) {
  return __uint_as_float(((unsigned)u) << 16);
}

__global__ __launch_bounds__(256) void hist_kernel(const int* __restrict__ dst,
                                                   int* __restrict__ cnt) {
  int e = blockIdx.x * 256 + threadIdx.x;
  if (e < N_EDGES) atomicAdd(&cnt[dst[e]], 1);
}

__global__ __launch_bounds__(256) void scan1_kernel(const int* __restrict__ cnt,
                                                    int* __restrict__ off,
                                                    int* __restrict__ bsum) {
  __shared__ int s[256];
  int i = blockIdx.x * 256 + threadIdx.x;
  int v = (i < N_NODES) ? cnt[i] : 0;
  s[threadIdx.x] = v;
  __syncthreads();
  for (int o = 1; o < 256; o <<= 1) {
    int t = (threadIdx.x >= o) ? s[threadIdx.x - o] : 0;
    __syncthreads();
    s[threadIdx.x] += t;
    __syncthreads();
  }
  if (i < N_NODES) off[i] = s[threadIdx.x] - v;
  if (threadIdx.x == 255) bsum[blockIdx.x] = s[255];
}

__global__ __launch_bounds__(256) void scan2_kernel(int* __restrict__ bsum) {
  __shared__ int s[256];
  int v = (threadIdx.x < NB_SCAN) ? bsum[threadIdx.x] : 0;
  s[threadIdx.x] = v;
  __syncthreads();
  for (int o = 1; o < 256; o <<= 1) {
    int t = (threadIdx.x >= o) ? s[threadIdx.x - o] : 0;
    __syncthreads();
    s[threadIdx.x] += t;
    __syncthreads();
  }
  if (threadIdx.x < NB_SCAN) bsum[threadIdx.x] = s[threadIdx.x] - v;
}

__global__ __launch_bounds__(256) void scan3_kernel(int* __restrict__ off,
                                                    const int* __restrict__ bsum,
                                                    int* __restrict__ cur) {
  int i = blockIdx.x * 256 + threadIdx.x;
  if (i < N_NODES) {
    int o = off[i] + bsum[blockIdx.x];
    off[i] = o;
    cur[i] = o;
  }
}

__global__ __launch_bounds__(256) void place_kernel(const int* __restrict__ src,
                                                    const int* __restrict__ dst,
                                                    int* __restrict__ cur,
                                                    int* __restrict__ csr) {
  int e = blockIdx.x * 256 + threadIdx.x;
  if (e < N_EDGES) {
    int pos = atomicAdd(&cur[dst[e]], 1);
    csr[pos] = src[e];
  }
}

// xwl[n,h] = bf16(x[n,:].W1l[h,:]);  xwr[n,h] = x[n,:].W1r[h,:] + b1[h]
// Weights in LDS as bf16 (33 KB total -> 4 blocks/CU); loop nest inverted so
// each LDS weight read is shared by 8 nodes.
__global__ __launch_bounds__(256) void xform1_kernel(
    const float* __restrict__ x, const float* __restrict__ W1l,
    const float* __restrict__ W1r, const float* __restrict__ b1,
    ushort* __restrict__ xwl, float* __restrict__ xwr) {
  __shared__ ushort sWl[IN_CH][HID + 1];  // 16640 B
  __shared__ ushort sWr[IN_CH][HID + 1];  // 16640 B
  for (int i = threadIdx.x; i < HID * IN_CH; i += 256) {
    int h = i >> 7, c = i & (IN_CH - 1);
    sWl[c][h] = f2bf(W1l[i]);
    sWr[c][h] = f2bf(W1r[i]);
  }
  __syncthreads();
  int wave = threadIdx.x >> 6, lane = threadIdx.x & 63;
  int n0 = blockIdx.x * 32 + wave * 8;
  if (n0 >= N_NODES) return;
  float bias = b1[lane];

  if (n0 + 8 <= N_NODES) {
    float accl[8], accr[8];
#pragma unroll
    for (int i = 0; i < 8; ++i) {
      accl[i] = 0.f;
      accr[i] = bias;
    }
    const float* xb = x + (size_t)n0 * IN_CH;
    for (int c = 0; c < IN_CH; c += 4) {
      float wl0 = bf2f(sWl[c + 0][lane]), wl1 = bf2f(sWl[c + 1][lane]);
      float wl2 = bf2f(sWl[c + 2][lane]), wl3 = bf2f(sWl[c + 3][lane]);
      float wr0 = bf2f(sWr[c + 0][lane]), wr1 = bf2f(sWr[c + 1][lane]);
      float wr2 = bf2f(sWr[c + 2][lane]), wr3 = bf2f(sWr[c + 3][lane]);
#pragma unroll
      for (int i = 0; i < 8; ++i) {
        const float4 xv =
            *reinterpret_cast<const float4*>(xb + (size_t)i * IN_CH + c);
        accl[i] = fmaf(xv.x, wl0, accl[i]);
        accr[i] = fmaf(xv.x, wr0, accr[i]);
        accl[i] = fmaf(xv.y, wl1, accl[i]);
        accr[i] = fmaf(xv.y, wr1, accr[i]);
        accl[i] = fmaf(xv.z, wl2, accl[i]);
        accr[i] = fmaf(xv.z, wr2, accr[i]);
        accl[i] = fmaf(xv.w, wl3, accl[i]);
        accr[i] = fmaf(xv.w, wr3, accr[i]);
      }
    }
#pragma unroll
    for (int i = 0; i < 8; ++i) {
      xwl[(size_t)(n0 + i) * HID + lane] = f2bf(accl[i]);
      xwr[(size_t)(n0 + i) * HID + lane] = accr[i];
    }
  } else {  // partial tail block (unused when N%8==0, kept for safety)
    for (int i = 0; i < 8; ++i) {
      int n = n0 + i;
      if (n >= N_NODES) return;
      const float* xr = x + (size_t)n * IN_CH;
      float al = 0.f, ar = bias;
#pragma unroll 16
      for (int c = 0; c < IN_CH; ++c) {
        float xv = xr[c];
        al = fmaf(xv, bf2f(sWl[c][lane]), al);
        ar = fmaf(xv, bf2f(sWr[c][lane]), ar);
      }
      xwl[(size_t)n * HID + lane] = f2bf(al);
      xwr[(size_t)n * HID + lane] = ar;
    }
  }
}

// h = relu(gather_mean(xwl) + xwr);  hw2 = bf16(h@W2l.T);  self2 = h@W2r.T+b2
__global__ __launch_bounds__(256) void agg1_kernel(
    const ushort* __restrict__ xwl, const float* __restrict__ xwr,
    const float* __restrict__ W2l, const float* __restrict__ W2r,
    const float* __restrict__ b2, const int* __restrict__ cnt,
    const int* __restrict__ off, const int* __restrict__ csr,
    ushort* __restrict__ hw2, float* __restrict__ self2) {
  __shared__ float sW2l[HID][OUT_CH + 1];  // 10496 B
  __shared__ float sW2r[HID][OUT_CH + 1];  // 10496 B
  __shared__ float sh1[4][HID];            // 1024 B
  for (int i = threadIdx.x; i < OUT_CH * HID; i += 256) {
    int o = i >> 6, c = i & (HID - 1);
    sW2l[c][o] = W2l[i];
    sW2r[c][o] = W2r[i];
  }
  __syncthreads();
  int wave = threadIdx.x >> 6, lane = threadIdx.x & 63;
  int n = blockIdx.x * 4 + wave;
  if (n >= N_NODES) return;

  int deg = cnt[n], base = off[n];
  float acc = 0.f;
  int k = 0;
  for (; k + 8 <= deg; k += 8) {  // 8-wide MLP gather
    int s0 = csr[base + k + 0], s1 = csr[base + k + 1];
    int s2 = csr[base + k + 2], s3 = csr[base + k + 3];
    int s4 = csr[base + k + 4], s5 = csr[base + k + 5];
    int s6 = csr[base + k + 6], s7 = csr[base + k + 7];
    float v0 = bf2f(xwl[(size_t)s0 * HID + lane]);
    float v1 = bf2f(xwl[(size_t)s1 * HID + lane]);
    float v2 = bf2f(xwl[(size_t)s2 * HID + lane]);
    float v3 = bf2f(xwl[(size_t)s3 * HID + lane]);
    float v4 = bf2f(xwl[(size_t)s4 * HID + lane]);
    float v5 = bf2f(xwl[(size_t)s5 * HID + lane]);
    float v6 = bf2f(xwl[(size_t)s6 * HID + lane]);
    float v7 = bf2f(xwl[(size_t)s7 * HID + lane]);
    acc += ((v0 + v1) + (v2 + v3)) + ((v4 + v5) + (v6 + v7));
  }
  if (k < deg) {  // masked 8-wide remainder
#pragma unroll
    for (int i = 0; i < 8; ++i) {
      int kk = k + i;
      int s_ = csr[base + (kk < deg ? kk : k)];
      float v = bf2f(xwl[(size_t)s_ * HID + lane]);
      if (kk < deg) acc += v;
    }
  }
  float inv = 1.0f / fmaxf((float)deg, 1.0f);
  float h = fmaxf(acc * inv + xwr[(size_t)n * HID + lane], 0.f);

  sh1[wave][lane] = h;  // wave-coherent, no barrier needed
  if (lane < OUT_CH) {
    float o2 = 0.f, s2v = b2[lane];
#pragma unroll 16
    for (int c = 0; c < HID; ++c) {
      float hv = sh1[wave][c];
      o2 = fmaf(hv, sW2l[c][lane], o2);
      s2v = fmaf(hv, sW2r[c][lane], s2v);
    }
    hw2[(size_t)n * OUT_CH + lane] = f2bf(o2);
    self2[(size_t)n * OUT_CH + lane] = s2v;
  }
}

// out = log_softmax(gather_mean(hw2) + self2)  — no LDS, no weights
__global__ __launch_bounds__(256) void agg2_kernel(
    const ushort* __restrict__ hw2, const float* __restrict__ self2,
    const int* __restrict__ cnt, const int* __restrict__ off,
    const int* __restrict__ csr, float* __restrict__ out) {
  int wave = threadIdx.x >> 6, lane = threadIdx.x & 63;
  int n = blockIdx.x * 4 + wave;
  if (n >= N_NODES) return;

  int deg = cnt[n], base = off[n];
  float logit = -1e30f;
  if (lane < OUT_CH) {
    float acc = 0.f;
    int k = 0;
    for (; k + 8 <= deg; k += 8) {
      int s0 = csr[base + k + 0], s1 = csr[base + k + 1];
      int s2 = csr[base + k + 2], s3 = csr[base + k + 3];
      int s4 = csr[base + k + 4], s5 = csr[base + k + 5];
      int s6 = csr[base + k + 6], s7 = csr[base + k + 7];
      float v0 = bf2f(hw2[(size_t)s0 * OUT_CH + lane]);
      float v1 = bf2f(hw2[(size_t)s1 * OUT_CH + lane]);
      float v2 = bf2f(hw2[(size_t)s2 * OUT_CH + lane]);
      float v3 = bf2f(hw2[(size_t)s3 * OUT_CH + lane]);
      float v4 = bf2f(hw2[(size_t)s4 * OUT_CH + lane]);
      float v5 = bf2f(hw2[(size_t)s5 * OUT_CH + lane]);
      float v6 = bf2f(hw2[(size_t)s6 * OUT_CH + lane]);
      float v7 = bf2f(hw2[(size_t)s7 * OUT_CH + lane]);
      acc += ((v0 + v1) + (v2 + v3)) + ((v4 + v5) + (v6 + v7));
    }
    if (k < deg) {
#pragma unroll
      for (int i = 0; i < 8; ++i) {
        int kk = k + i;
        int s_ = csr[base + (kk < deg ? kk : k)];
        float v = bf2f(hw2[(size_t)s_ * OUT_CH + lane]);
        if (kk < deg) acc += v;
      }
    }
    logit = acc / fmaxf((float)deg, 1.0f) + self2[(size_t)n * OUT_CH + lane];
  }
  // log_softmax over 40 valid lanes (idle lanes carry identity elements)
  float m = logit;
  for (int o = 32; o; o >>= 1) m = fmaxf(m, __shfl_xor(m, o));
  float e = (lane < OUT_CH) ? expf(logit - m) : 0.f;
  float ssum = e;
  for (int o = 32; o; o >>= 1) ssum += __shfl_xor(ssum, o);
  float lse = logf(ssum);
  if (lane < OUT_CH) out[(size_t)n * OUT_CH + lane] = logit - m - lse;
}

extern "C" void kernel_launch(void* const* d_in, const int* in_sizes, int n_in,
                              void* d_out, int out_size, void* d_ws, size_t ws_size,
                              hipStream_t stream) {
  const float* x   = (const float*)d_in[0];
  const int*   ei  = (const int*)d_in[1];
  const float* W1l = (const float*)d_in[2];
  const float* b1  = (const float*)d_in[3];
  const float* W1r = (const float*)d_in[4];
  const float* W2l = (const float*)d_in[5];
  const float* b2  = (const float*)d_in[6];
  const float* W2r = (const float*)d_in[7];
  float* out = (float*)d_out;

  const int* src = ei;            // edge_index[0]
  const int* dst = ei + N_EDGES;  // edge_index[1]

  // ws layout: f32 arrays first, then bf16, then ints
  float* xwr   = (float*)d_ws;                             // [N*HID] f32
  float* self2 = xwr + (size_t)N_NODES * HID;              // [N*OUT_CH] f32
  ushort* xwl  = (ushort*)(self2 + (size_t)N_NODES * OUT_CH);  // [N*HID] bf16
  ushort* hw2  = xwl + (size_t)N_NODES * HID;              // [N*OUT_CH] bf16
  int* cnt  = (int*)(hw2 + (size_t)N_NODES * OUT_CH);      // [N]
  int* off  = cnt + N_NODES;                               // [N]
  int* cur  = off + N_NODES;                               // [N]
  int* bsum = cur + N_NODES;                               // [256]
  int* csr  = bsum + 256;                                  // [E]

  hipMemsetAsync(cnt, 0, sizeof(int) * N_NODES, stream);

  const int EB = (N_EDGES + 255) / 256;  // 3125
  hist_kernel<<<EB, 256, 0, stream>>>(dst, cnt);
  scan1_kernel<<<NB_SCAN, 256, 0, stream>>>(cnt, off, bsum);
  scan2_kernel<<<1, 256, 0, stream>>>(bsum);
  scan3_kernel<<<NB_SCAN, 256, 0, stream>>>(off, bsum, cur);
  place_kernel<<<EB, 256, 0, stream>>>(src, dst, cur, csr);

  xform1_kernel<<<(N_NODES + 31) / 32, 256, 0, stream>>>(x, W1l, W1r, b1, xwl,
                                                         xwr);
  agg1_kernel<<<(N_NODES + 3) / 4, 256, 0, stream>>>(xwl, xwr, W2l, W2r, b2,
                                                     cnt, off, csr, hw2, self2);
  agg2_kernel<<<(N_NODES + 3) / 4, 256, 0, stream>>>(hw2, self2, cnt, off, csr,
                                                     out);
}

// Round 9
// 230.830 us; speedup vs baseline: 3.2884x; 1.0790x over previous
//
#include <hip/hip_runtime.h>

#define N_NODES 50000
#define N_EDGES 800000
#define IN_CH 128
#define HID 64
#define OUT_CH 40
#define NB_SCAN 196  // ceil(50000/256)

// ---------------------------------------------------------------------------
// CSR gather, no fp atomics, transform-before-aggregate:
//   xform1: xwl = bf16(x@W1l.T), xwr = x@W1r.T + b1
//           (x tile staged in LDS via coalesced loads -> inner loop reads are
//            LDS broadcasts, not lane-uniform global loads; weights packed
//            2xbf16 per uint in LDS)
//   agg1:   h = relu(gather_mean(xwl) + xwr); hw2 = bf16(h@W2l.T);
//           self2 = h@W2r.T + b2
//   agg2:   out = log_softmax(gather_mean(hw2) + self2)
// ---------------------------------------------------------------------------

__device__ __forceinline__ ushort f2bf(float f) {
  unsigned u = __float_as_uint(f);
  return (ushort)((u + 0x7FFF + ((u >> 16) & 1)) >> 16);  // RNE
}
__device__ __forceinline__ float bf2f(ushort u) {
  return __uint_as_float(((unsigned)u) << 16);
}
__device__ __forceinline__ float bflo(unsigned u) {  // bf16 in low half
  return __uint_as_float(u << 16);
}
__device__ __forceinline__ float bfhi(unsigned u) {  // bf16 in high half
  return __uint_as_float(u & 0xFFFF0000u);
}

__global__ __launch_bounds__(256) void hist_kernel(const int* __restrict__ dst,
                                                   int* __restrict__ cnt) {
  int e = blockIdx.x * 256 + threadIdx.x;
  if (e < N_EDGES) atomicAdd(&cnt[dst[e]], 1);
}

__global__ __launch_bounds__(256) void scan1_kernel(const int* __restrict__ cnt,
                                                    int* __restrict__ off,
                                                    int* __restrict__ bsum) {
  __shared__ int s[256];
  int i = blockIdx.x * 256 + threadIdx.x;
  int v = (i < N_NODES) ? cnt[i] : 0;
  s[threadIdx.x] = v;
  __syncthreads();
  for (int o = 1; o < 256; o <<= 1) {
    int t = (threadIdx.x >= o) ? s[threadIdx.x - o] : 0;
    __syncthreads();
    s[threadIdx.x] += t;
    __syncthreads();
  }
  if (i < N_NODES) off[i] = s[threadIdx.x] - v;
  if (threadIdx.x == 255) bsum[blockIdx.x] = s[255];
}

__global__ __launch_bounds__(256) void scan2_kernel(int* __restrict__ bsum) {
  __shared__ int s[256];
  int v = (threadIdx.x < NB_SCAN) ? bsum[threadIdx.x] : 0;
  s[threadIdx.x] = v;
  __syncthreads();
  for (int o = 1; o < 256; o <<= 1) {
    int t = (threadIdx.x >= o) ? s[threadIdx.x - o] : 0;
    __syncthreads();
    s[threadIdx.x] += t;
    __syncthreads();
  }
  if (threadIdx.x < NB_SCAN) bsum[threadIdx.x] = s[threadIdx.x] - v;
}

__global__ __launch_bounds__(256) void scan3_kernel(int* __restrict__ off,
                                                    const int* __restrict__ bsum,
                                                    int* __restrict__ cur) {
  int i = blockIdx.x * 256 + threadIdx.x;
  if (i < N_NODES) {
    int o = off[i] + bsum[blockIdx.x];
    off[i] = o;
    cur[i] = o;
  }
}

__global__ __launch_bounds__(256) void place_kernel(const int* __restrict__ src,
                                                    const int* __restrict__ dst,
                                                    int* __restrict__ cur,
                                                    int* __restrict__ csr) {
  int e = blockIdx.x * 256 + threadIdx.x;
  if (e < N_EDGES) {
    int pos = atomicAdd(&cur[dst[e]], 1);
    csr[pos] = src[e];
  }
}

// xwl[n,h] = bf16(x[n,:].W1l[h,:]);  xwr[n,h] = x[n,:].W1r[h,:] + b1[h]
// 32-node tile per block. x staged in LDS (coalesced), weights 2xbf16/uint.
__global__ __launch_bounds__(256) void xform1_kernel(
    const float* __restrict__ x, const float* __restrict__ W1l,
    const float* __restrict__ W1r, const float* __restrict__ b1,
    ushort* __restrict__ xwl, float* __restrict__ xwr) {
  __shared__ unsigned sWl[IN_CH / 2][HID + 1];  // 16640 B (2 bf16 per uint)
  __shared__ unsigned sWr[IN_CH / 2][HID + 1];  // 16640 B
  __shared__ float sx[32][IN_CH];               // 16384 B
  // stage weights: thread reads coalesced float2 of one W row, packs
  for (int i = threadIdx.x; i < HID * (IN_CH / 2); i += 256) {
    int h = i >> 6, c2 = i & 63;  // c2 indexes channel pairs
    float a = W1l[h * IN_CH + 2 * c2], b = W1l[h * IN_CH + 2 * c2 + 1];
    sWl[c2][h] = (unsigned)f2bf(a) | ((unsigned)f2bf(b) << 16);
    float c = W1r[h * IN_CH + 2 * c2], d = W1r[h * IN_CH + 2 * c2 + 1];
    sWr[c2][h] = (unsigned)f2bf(c) | ((unsigned)f2bf(d) << 16);
  }
  // stage x tile: 32 nodes x 128 ch, coalesced float4
  int nblk = blockIdx.x * 32;
  for (int s = threadIdx.x; s < 32 * (IN_CH / 4); s += 256) {
    int node = s >> 5, c4 = s & 31;
    int n = nblk + node;
    float4 v = make_float4(0.f, 0.f, 0.f, 0.f);
    if (n < N_NODES)
      v = *reinterpret_cast<const float4*>(x + (size_t)n * IN_CH + c4 * 4);
    *reinterpret_cast<float4*>(&sx[node][c4 * 4]) = v;
  }
  __syncthreads();

  int wave = threadIdx.x >> 6, lane = threadIdx.x & 63;
  int n0 = nblk + wave * 8;
  if (n0 >= N_NODES) return;
  float bias = b1[lane];

  if (n0 + 8 <= N_NODES) {
    float accl[8], accr[8];
#pragma unroll
    for (int i = 0; i < 8; ++i) {
      accl[i] = 0.f;
      accr[i] = bias;
    }
    const int nb = wave * 8;
    for (int c = 0; c < IN_CH; c += 4) {
      unsigned ul0 = sWl[(c >> 1) + 0][lane], ul1 = sWl[(c >> 1) + 1][lane];
      unsigned ur0 = sWr[(c >> 1) + 0][lane], ur1 = sWr[(c >> 1) + 1][lane];
      float wl0 = bflo(ul0), wl1 = bfhi(ul0), wl2 = bflo(ul1), wl3 = bfhi(ul1);
      float wr0 = bflo(ur0), wr1 = bfhi(ur0), wr2 = bflo(ur1), wr3 = bfhi(ur1);
#pragma unroll
      for (int i = 0; i < 8; ++i) {
        const float4 xv = *reinterpret_cast<const float4*>(&sx[nb + i][c]);
        accl[i] = fmaf(xv.x, wl0, accl[i]);
        accr[i] = fmaf(xv.x, wr0, accr[i]);
        accl[i] = fmaf(xv.y, wl1, accl[i]);
        accr[i] = fmaf(xv.y, wr1, accr[i]);
        accl[i] = fmaf(xv.z, wl2, accl[i]);
        accr[i] = fmaf(xv.z, wr2, accr[i]);
        accl[i] = fmaf(xv.w, wl3, accl[i]);
        accr[i] = fmaf(xv.w, wr3, accr[i]);
      }
    }
#pragma unroll
    for (int i = 0; i < 8; ++i) {
      xwl[(size_t)(n0 + i) * HID + lane] = f2bf(accl[i]);
      xwr[(size_t)(n0 + i) * HID + lane] = accr[i];
    }
  } else {  // partial group (unreachable for N=50000, kept for safety)
    for (int i = 0; i < 8; ++i) {
      int n = n0 + i;
      if (n >= N_NODES) return;
      float al = 0.f, ar = bias;
      for (int c = 0; c < IN_CH; c += 2) {
        unsigned ul = sWl[c >> 1][lane], ur = sWr[c >> 1][lane];
        float x0 = sx[wave * 8 + i][c], x1 = sx[wave * 8 + i][c + 1];
        al = fmaf(x0, bflo(ul), al);
        ar = fmaf(x0, bflo(ur), ar);
        al = fmaf(x1, bfhi(ul), al);
        ar = fmaf(x1, bfhi(ur), ar);
      }
      xwl[(size_t)n * HID + lane] = f2bf(al);
      xwr[(size_t)n * HID + lane] = ar;
    }
  }
}

// h = relu(gather_mean(xwl) + xwr);  hw2 = bf16(h@W2l.T);  self2 = h@W2r.T+b2
__global__ __launch_bounds__(256) void agg1_kernel(
    const ushort* __restrict__ xwl, const float* __restrict__ xwr,
    const float* __restrict__ W2l, const float* __restrict__ W2r,
    const float* __restrict__ b2, const int* __restrict__ cnt,
    const int* __restrict__ off, const int* __restrict__ csr,
    ushort* __restrict__ hw2, float* __restrict__ self2) {
  __shared__ float sW2l[HID][OUT_CH + 1];  // 10496 B
  __shared__ float sW2r[HID][OUT_CH + 1];  // 10496 B
  __shared__ float sh1[4][HID];            // 1024 B
  for (int i = threadIdx.x; i < OUT_CH * HID; i += 256) {
    int o = i >> 6, c = i & (HID - 1);
    sW2l[c][o] = W2l[i];
    sW2r[c][o] = W2r[i];
  }
  __syncthreads();
  int wave = threadIdx.x >> 6, lane = threadIdx.x & 63;
  int n = blockIdx.x * 4 + wave;
  if (n >= N_NODES) return;

  int deg = cnt[n], base = off[n];
  float acc = 0.f;
  int k = 0;
  for (; k + 8 <= deg; k += 8) {  // 8-wide MLP gather
    int s0 = csr[base + k + 0], s1 = csr[base + k + 1];
    int s2 = csr[base + k + 2], s3 = csr[base + k + 3];
    int s4 = csr[base + k + 4], s5 = csr[base + k + 5];
    int s6 = csr[base + k + 6], s7 = csr[base + k + 7];
    float v0 = bf2f(xwl[(size_t)s0 * HID + lane]);
    float v1 = bf2f(xwl[(size_t)s1 * HID + lane]);
    float v2 = bf2f(xwl[(size_t)s2 * HID + lane]);
    float v3 = bf2f(xwl[(size_t)s3 * HID + lane]);
    float v4 = bf2f(xwl[(size_t)s4 * HID + lane]);
    float v5 = bf2f(xwl[(size_t)s5 * HID + lane]);
    float v6 = bf2f(xwl[(size_t)s6 * HID + lane]);
    float v7 = bf2f(xwl[(size_t)s7 * HID + lane]);
    acc += ((v0 + v1) + (v2 + v3)) + ((v4 + v5) + (v6 + v7));
  }
  if (k < deg) {  // masked 8-wide remainder
#pragma unroll
    for (int i = 0; i < 8; ++i) {
      int kk = k + i;
      int s_ = csr[base + (kk < deg ? kk : k)];
      float v = bf2f(xwl[(size_t)s_ * HID + lane]);
      if (kk < deg) acc += v;
    }
  }
  float inv = 1.0f / fmaxf((float)deg, 1.0f);
  float h = fmaxf(acc * inv + xwr[(size_t)n * HID + lane], 0.f);

  sh1[wave][lane] = h;  // wave-coherent, no barrier needed
  if (lane < OUT_CH) {
    float o2 = 0.f, s2v = b2[lane];
#pragma unroll 16
    for (int c = 0; c < HID; ++c) {
      float hv = sh1[wave][c];
      o2 = fmaf(hv, sW2l[c][lane], o2);
      s2v = fmaf(hv, sW2r[c][lane], s2v);
    }
    hw2[(size_t)n * OUT_CH + lane] = f2bf(o2);
    self2[(size_t)n * OUT_CH + lane] = s2v;
  }
}

// out = log_softmax(gather_mean(hw2) + self2)  — no LDS, no weights
__global__ __launch_bounds__(256) void agg2_kernel(
    const ushort* __restrict__ hw2, const float* __restrict__ self2,
    const int* __restrict__ cnt, const int* __restrict__ off,
    const int* __restrict__ csr, float* __restrict__ out) {
  int wave = threadIdx.x >> 6, lane = threadIdx.x & 63;
  int n = blockIdx.x * 4 + wave;
  if (n >= N_NODES) return;

  int deg = cnt[n], base = off[n];
  float logit = -1e30f;
  if (lane < OUT_CH) {
    float acc = 0.f;
    int k = 0;
    for (; k + 8 <= deg; k += 8) {
      int s0 = csr[base + k + 0], s1 = csr[base + k + 1];
      int s2 = csr[base + k + 2], s3 = csr[base + k + 3];
      int s4 = csr[base + k + 4], s5 = csr[base + k + 5];
      int s6 = csr[base + k + 6], s7 = csr[base + k + 7];
      float v0 = bf2f(hw2[(size_t)s0 * OUT_CH + lane]);
      float v1 = bf2f(hw2[(size_t)s1 * OUT_CH + lane]);
      float v2 = bf2f(hw2[(size_t)s2 * OUT_CH + lane]);
      float v3 = bf2f(hw2[(size_t)s3 * OUT_CH + lane]);
      float v4 = bf2f(hw2[(size_t)s4 * OUT_CH + lane]);
      float v5 = bf2f(hw2[(size_t)s5 * OUT_CH + lane]);
      float v6 = bf2f(hw2[(size_t)s6 * OUT_CH + lane]);
      float v7 = bf2f(hw2[(size_t)s7 * OUT_CH + lane]);
      acc += ((v0 + v1) + (v2 + v3)) + ((v4 + v5) + (v6 + v7));
    }
    if (k < deg) {
#pragma unroll
      for (int i = 0; i < 8; ++i) {
        int kk = k + i;
        int s_ = csr[base + (kk < deg ? kk : k)];
        float v = bf2f(hw2[(size_t)s_ * OUT_CH + lane]);
        if (kk < deg) acc += v;
      }
    }
    logit = acc / fmaxf((float)deg, 1.0f) + self2[(size_t)n * OUT_CH + lane];
  }
  // log_softmax over 40 valid lanes (idle lanes carry identity elements)
  float m = logit;
  for (int o = 32; o; o >>= 1) m = fmaxf(m, __shfl_xor(m, o));
  float e = (lane < OUT_CH) ? expf(logit - m) : 0.f;
  float ssum = e;
  for (int o = 32; o; o >>= 1) ssum += __shfl_xor(ssum, o);
  float lse = logf(ssum);
  if (lane < OUT_CH) out[(size_t)n * OUT_CH + lane] = logit - m - lse;
}

extern "C" void kernel_launch(void* const* d_in, const int* in_sizes, int n_in,
                              void* d_out, int out_size, void* d_ws, size_t ws_size,
                              hipStream_t stream) {
  const float* x   = (const float*)d_in[0];
  const int*   ei  = (const int*)d_in[1];
  const float* W1l = (const float*)d_in[2];
  const float* b1  = (const float*)d_in[3];
  const float* W1r = (const float*)d_in[4];
  const float* W2l = (const float*)d_in[5];
  const float* b2  = (const float*)d_in[6];
  const float* W2r = (const float*)d_in[7];
  float* out = (float*)d_out;

  const int* src = ei;            // edge_index[0]
  const int* dst = ei + N_EDGES;  // edge_index[1]

  // ws layout: f32 arrays first, then bf16, then ints
  float* xwr   = (float*)d_ws;                             // [N*HID] f32
  float* self2 = xwr + (size_t)N_NODES * HID;              // [N*OUT_CH] f32
  ushort* xwl  = (ushort*)(self2 + (size_t)N_NODES * OUT_CH);  // [N*HID] bf16
  ushort* hw2  = xwl + (size_t)N_NODES * HID;              // [N*OUT_CH] bf16
  int* cnt  = (int*)(hw2 + (size_t)N_NODES * OUT_CH);      // [N]
  int* off  = cnt + N_NODES;                               // [N]
  int* cur  = off + N_NODES;                               // [N]
  int* bsum = cur + N_NODES;                               // [256]
  int* csr  = bsum + 256;                                  // [E]

  hipMemsetAsync(cnt, 0, sizeof(int) * N_NODES, stream);

  const int EB = (N_EDGES + 255) / 256;  // 3125
  hist_kernel<<<EB, 256, 0, stream>>>(dst, cnt);
  scan1_kernel<<<NB_SCAN, 256, 0, stream>>>(cnt, off, bsum);
  scan2_kernel<<<1, 256, 0, stream>>>(bsum);
  scan3_kernel<<<NB_SCAN, 256, 0, stream>>>(off, bsum, cur);
  place_kernel<<<EB, 256, 0, stream>>>(src, dst, cur, csr);

  xform1_kernel<<<(N_NODES + 31) / 32, 256, 0, stream>>>(x, W1l, W1r, b1, xwl,
                                                         xwr);
  agg1_kernel<<<(N_NODES + 3) / 4, 256, 0, stream>>>(xwl, xwr, W2l, W2r, b2,
                                                     cnt, off, csr, hw2, self2);
  agg2_kernel<<<(N_NODES + 3) / 4, 256, 0, stream>>>(hw2, self2, cnt, off, csr,
                                                     out);
}

// Round 10
// 218.219 us; speedup vs baseline: 3.4785x; 1.0578x over previous
//
#include <hip/hip_runtime.h>

#define N_NODES 50000
#define N_EDGES 800000
#define IN_CH 128
#define HID 64
#define OUT_CH 40
#define NB_SCAN 196  // ceil(50000/256)

// ---------------------------------------------------------------------------
// CSR gather, no fp atomics, transform-before-aggregate. All GEMV-style
// projections live in weight-amortized "xform" kernels (8 nodes/wave share
// each LDS weight read); the gather kernels are lean (no LDS, no FMA loops).
//   xform1: xwl = bf16(x@W1l.T), xwr = x@W1r.T + b1
//   agg1:   h1 = relu(gather_mean(xwl) + xwr)          [paired-edge gather]
//   xform2: hw2 = bf16(h1@W2l.T), self2 = h1@W2r.T + b2
//   agg2:   out = log_softmax(gather_mean(hw2) + self2)
// ---------------------------------------------------------------------------

__device__ __forceinline__ ushort f2bf(float f) {
  unsigned u = __float_as_uint(f);
  return (ushort)((u + 0x7FFF + ((u >> 16) & 1)) >> 16);  // RNE
}
__device__ __forceinline__ float bf2f(ushort u) {
  return __uint_as_float(((unsigned)u) << 16);
}
__device__ __forceinline__ float bflo(unsigned u) {  // bf16 in low half
  return __uint_as_float(u << 16);
}
__device__ __forceinline__ float bfhi(unsigned u) {  // bf16 in high half
  return __uint_as_float(u & 0xFFFF0000u);
}

__global__ __launch_bounds__(256) void hist_kernel(const int* __restrict__ dst,
                                                   int* __restrict__ cnt) {
  int e = blockIdx.x * 256 + threadIdx.x;
  if (e < N_EDGES) atomicAdd(&cnt[dst[e]], 1);
}

__global__ __launch_bounds__(256) void scan1_kernel(const int* __restrict__ cnt,
                                                    int* __restrict__ off,
                                                    int* __restrict__ bsum) {
  __shared__ int s[256];
  int i = blockIdx.x * 256 + threadIdx.x;
  int v = (i < N_NODES) ? cnt[i] : 0;
  s[threadIdx.x] = v;
  __syncthreads();
  for (int o = 1; o < 256; o <<= 1) {
    int t = (threadIdx.x >= o) ? s[threadIdx.x - o] : 0;
    __syncthreads();
    s[threadIdx.x] += t;
    __syncthreads();
  }
  if (i < N_NODES) off[i] = s[threadIdx.x] - v;
  if (threadIdx.x == 255) bsum[blockIdx.x] = s[255];
}

__global__ __launch_bounds__(256) void scan2_kernel(int* __restrict__ bsum) {
  __shared__ int s[256];
  int v = (threadIdx.x < NB_SCAN) ? bsum[threadIdx.x] : 0;
  s[threadIdx.x] = v;
  __syncthreads();
  for (int o = 1; o < 256; o <<= 1) {
    int t = (threadIdx.x >= o) ? s[threadIdx.x - o] : 0;
    __syncthreads();
    s[threadIdx.x] += t;
    __syncthreads();
  }
  if (threadIdx.x < NB_SCAN) bsum[threadIdx.x] = s[threadIdx.x] - v;
}

__global__ __launch_bounds__(256) void scan3_kernel(int* __restrict__ off,
                                                    const int* __restrict__ bsum,
                                                    int* __restrict__ cur) {
  int i = blockIdx.x * 256 + threadIdx.x;
  if (i < N_NODES) {
    int o = off[i] + bsum[blockIdx.x];
    off[i] = o;
    cur[i] = o;
  }
}

__global__ __launch_bounds__(256) void place_kernel(const int* __restrict__ src,
                                                    const int* __restrict__ dst,
                                                    int* __restrict__ cur,
                                                    int* __restrict__ csr) {
  int e = blockIdx.x * 256 + threadIdx.x;
  if (e < N_EDGES) {
    int pos = atomicAdd(&cur[dst[e]], 1);
    csr[pos] = src[e];
  }
}

// xwl[n,h] = bf16(x[n,:].W1l[h,:]);  xwr[n,h] = x[n,:].W1r[h,:] + b1[h]
// 32-node tile per block. x staged in LDS (coalesced), weights 2xbf16/uint.
__global__ __launch_bounds__(256) void xform1_kernel(
    const float* __restrict__ x, const float* __restrict__ W1l,
    const float* __restrict__ W1r, const float* __restrict__ b1,
    ushort* __restrict__ xwl, float* __restrict__ xwr) {
  __shared__ unsigned sWl[IN_CH / 2][HID + 1];  // 16640 B (2 bf16 per uint)
  __shared__ unsigned sWr[IN_CH / 2][HID + 1];  // 16640 B
  __shared__ float sx[32][IN_CH];               // 16384 B
  for (int i = threadIdx.x; i < HID * (IN_CH / 2); i += 256) {
    int h = i >> 6, c2 = i & 63;
    float a = W1l[h * IN_CH + 2 * c2], b = W1l[h * IN_CH + 2 * c2 + 1];
    sWl[c2][h] = (unsigned)f2bf(a) | ((unsigned)f2bf(b) << 16);
    float c = W1r[h * IN_CH + 2 * c2], d = W1r[h * IN_CH + 2 * c2 + 1];
    sWr[c2][h] = (unsigned)f2bf(c) | ((unsigned)f2bf(d) << 16);
  }
  int nblk = blockIdx.x * 32;
  for (int s = threadIdx.x; s < 32 * (IN_CH / 4); s += 256) {
    int node = s >> 5, c4 = s & 31;
    int n = nblk + node;
    float4 v = make_float4(0.f, 0.f, 0.f, 0.f);
    if (n < N_NODES)
      v = *reinterpret_cast<const float4*>(x + (size_t)n * IN_CH + c4 * 4);
    *reinterpret_cast<float4*>(&sx[node][c4 * 4]) = v;
  }
  __syncthreads();

  int wave = threadIdx.x >> 6, lane = threadIdx.x & 63;
  int n0 = nblk + wave * 8;
  if (n0 >= N_NODES) return;
  float bias = b1[lane];

  if (n0 + 8 <= N_NODES) {
    float accl[8], accr[8];
#pragma unroll
    for (int i = 0; i < 8; ++i) {
      accl[i] = 0.f;
      accr[i] = bias;
    }
    const int nb = wave * 8;
    for (int c = 0; c < IN_CH; c += 4) {
      unsigned ul0 = sWl[(c >> 1) + 0][lane], ul1 = sWl[(c >> 1) + 1][lane];
      unsigned ur0 = sWr[(c >> 1) + 0][lane], ur1 = sWr[(c >> 1) + 1][lane];
      float wl0 = bflo(ul0), wl1 = bfhi(ul0), wl2 = bflo(ul1), wl3 = bfhi(ul1);
      float wr0 = bflo(ur0), wr1 = bfhi(ur0), wr2 = bflo(ur1), wr3 = bfhi(ur1);
#pragma unroll
      for (int i = 0; i < 8; ++i) {
        const float4 xv = *reinterpret_cast<const float4*>(&sx[nb + i][c]);
        accl[i] = fmaf(xv.x, wl0, accl[i]);
        accr[i] = fmaf(xv.x, wr0, accr[i]);
        accl[i] = fmaf(xv.y, wl1, accl[i]);
        accr[i] = fmaf(xv.y, wr1, accr[i]);
        accl[i] = fmaf(xv.z, wl2, accl[i]);
        accr[i] = fmaf(xv.z, wr2, accr[i]);
        accl[i] = fmaf(xv.w, wl3, accl[i]);
        accr[i] = fmaf(xv.w, wr3, accr[i]);
      }
    }
#pragma unroll
    for (int i = 0; i < 8; ++i) {
      xwl[(size_t)(n0 + i) * HID + lane] = f2bf(accl[i]);
      xwr[(size_t)(n0 + i) * HID + lane] = accr[i];
    }
  } else {  // partial group (unreachable for N=50000, kept for safety)
    for (int i = 0; i < 8; ++i) {
      int n = n0 + i;
      if (n >= N_NODES) return;
      float al = 0.f, ar = bias;
      for (int c = 0; c < IN_CH; c += 2) {
        unsigned ul = sWl[c >> 1][lane], ur = sWr[c >> 1][lane];
        float x0 = sx[wave * 8 + i][c], x1 = sx[wave * 8 + i][c + 1];
        al = fmaf(x0, bflo(ul), al);
        ar = fmaf(x0, bflo(ur), ar);
        al = fmaf(x1, bfhi(ul), al);
        ar = fmaf(x1, bfhi(ur), ar);
      }
      xwl[(size_t)n * HID + lane] = f2bf(al);
      xwr[(size_t)n * HID + lane] = ar;
    }
  }
}

// h1 = relu(gather_mean(xwl) + xwr) — lean gather, no LDS.
// Lane l: channel pair 2*(l&31), edge parity l>>5 (even/odd edges).
// Per edge-pair one uint load per lane; shfl_xor(32) merges the halves.
__global__ __launch_bounds__(256) void agg1_kernel(
    const ushort* __restrict__ xwl, const float* __restrict__ xwr,
    const int* __restrict__ cnt, const int* __restrict__ off,
    const int* __restrict__ csr, float* __restrict__ h1) {
  int wave = threadIdx.x >> 6, lane = threadIdx.x & 63;
  int n = blockIdx.x * 4 + wave;
  if (n >= N_NODES) return;

  int deg = cnt[n], base = off[n];
  int half = lane >> 5;    // 0: even edges, 1: odd edges
  int cp = lane & 31;      // channel pair index
  float ax = 0.f, ay = 0.f;

  if (deg > 0) {
    int k = 0;
    for (; k + 8 <= deg; k += 8) {  // 4 edge-pairs per iteration
      int e0 = csr[base + k + 0 + half];
      int e1 = csr[base + k + 2 + half];
      int e2 = csr[base + k + 4 + half];
      int e3 = csr[base + k + 6 + half];
      unsigned u0 = *reinterpret_cast<const unsigned*>(
          xwl + (size_t)e0 * HID + 2 * cp);
      unsigned u1 = *reinterpret_cast<const unsigned*>(
          xwl + (size_t)e1 * HID + 2 * cp);
      unsigned u2 = *reinterpret_cast<const unsigned*>(
          xwl + (size_t)e2 * HID + 2 * cp);
      unsigned u3 = *reinterpret_cast<const unsigned*>(
          xwl + (size_t)e3 * HID + 2 * cp);
      ax += (bflo(u0) + bflo(u1)) + (bflo(u2) + bflo(u3));
      ay += (bfhi(u0) + bfhi(u1)) + (bfhi(u2) + bfhi(u3));
    }
    if (k < deg) {  // masked remainder (<8 edges)
#pragma unroll
      for (int j = 0; j < 4; ++j) {
        int idx = k + 2 * j + half;
        bool valid = idx < deg;
        int e = csr[base + (valid ? idx : 0)];
        unsigned u = *reinterpret_cast<const unsigned*>(
            xwl + (size_t)e * HID + 2 * cp);
        if (valid) {
          ax += bflo(u);
          ay += bfhi(u);
        }
      }
    }
    // merge even/odd halves (both halves end up with the full sum)
    ax += __shfl_xor(ax, 32);
    ay += __shfl_xor(ay, 32);
  }

  float inv = 1.0f / fmaxf((float)deg, 1.0f);
  const float2 s =
      *reinterpret_cast<const float2*>(xwr + (size_t)n * HID + 2 * cp);
  float2 h;
  h.x = fmaxf(ax * inv + s.x, 0.f);
  h.y = fmaxf(ay * inv + s.y, 0.f);
  if (half == 0)
    *reinterpret_cast<float2*>(h1 + (size_t)n * HID + 2 * cp) = h;
}

// hw2[n,o] = bf16(h1[n,:].W2l[o,:]);  self2[n,o] = h1[n,:].W2r[o,:] + b2[o]
// xform1 structure: 32-node h tile in LDS, packed 2xbf16 weights, 8 nodes/wave.
__global__ __launch_bounds__(256) void xform2_kernel(
    const float* __restrict__ h1, const float* __restrict__ W2l,
    const float* __restrict__ W2r, const float* __restrict__ b2,
    ushort* __restrict__ hw2, float* __restrict__ self2) {
  __shared__ unsigned sWl[HID / 2][OUT_CH + 1];  // 5248 B
  __shared__ unsigned sWr[HID / 2][OUT_CH + 1];  // 5248 B
  __shared__ float sh[32][HID];                  // 8192 B
  for (int i = threadIdx.x; i < OUT_CH * (HID / 2); i += 256) {
    int o = i >> 5, c2 = i & 31;
    float a = W2l[o * HID + 2 * c2], b = W2l[o * HID + 2 * c2 + 1];
    sWl[c2][o] = (unsigned)f2bf(a) | ((unsigned)f2bf(b) << 16);
    float c = W2r[o * HID + 2 * c2], d = W2r[o * HID + 2 * c2 + 1];
    sWr[c2][o] = (unsigned)f2bf(c) | ((unsigned)f2bf(d) << 16);
  }
  int nblk = blockIdx.x * 32;
  for (int s = threadIdx.x; s < 32 * (HID / 4); s += 256) {
    int node = s >> 4, c4 = s & 15;
    int n = nblk + node;
    float4 v = make_float4(0.f, 0.f, 0.f, 0.f);
    if (n < N_NODES)
      v = *reinterpret_cast<const float4*>(h1 + (size_t)n * HID + c4 * 4);
    *reinterpret_cast<float4*>(&sh[node][c4 * 4]) = v;
  }
  __syncthreads();

  int wave = threadIdx.x >> 6, lane = threadIdx.x & 63;
  int n0 = nblk + wave * 8;
  if (n0 >= N_NODES || lane >= OUT_CH) return;
  float bias = b2[lane];

  float accl[8], accr[8];
#pragma unroll
  for (int i = 0; i < 8; ++i) {
    accl[i] = 0.f;
    accr[i] = bias;
  }
  const int nb = wave * 8;
  int nvalid = min(8, N_NODES - n0);
  for (int c = 0; c < HID; c += 4) {
    unsigned ul0 = sWl[(c >> 1) + 0][lane], ul1 = sWl[(c >> 1) + 1][lane];
    unsigned ur0 = sWr[(c >> 1) + 0][lane], ur1 = sWr[(c >> 1) + 1][lane];
    float wl0 = bflo(ul0), wl1 = bfhi(ul0), wl2 = bflo(ul1), wl3 = bfhi(ul1);
    float wr0 = bflo(ur0), wr1 = bfhi(ur0), wr2 = bflo(ur1), wr3 = bfhi(ur1);
#pragma unroll
    for (int i = 0; i < 8; ++i) {
      const float4 hv = *reinterpret_cast<const float4*>(&sh[nb + i][c]);
      accl[i] = fmaf(hv.x, wl0, accl[i]);
      accr[i] = fmaf(hv.x, wr0, accr[i]);
      accl[i] = fmaf(hv.y, wl1, accl[i]);
      accr[i] = fmaf(hv.y, wr1, accr[i]);
      accl[i] = fmaf(hv.z, wl2, accl[i]);
      accr[i] = fmaf(hv.z, wr2, accr[i]);
      accl[i] = fmaf(hv.w, wl3, accl[i]);
      accr[i] = fmaf(hv.w, wr3, accr[i]);
    }
  }
  for (int i = 0; i < nvalid; ++i) {
    hw2[(size_t)(n0 + i) * OUT_CH + lane] = f2bf(accl[i]);
    self2[(size_t)(n0 + i) * OUT_CH + lane] = accr[i];
  }
}

// out = log_softmax(gather_mean(hw2) + self2)  — no LDS, no weights
__global__ __launch_bounds__(256) void agg2_kernel(
    const ushort* __restrict__ hw2, const float* __restrict__ self2,
    const int* __restrict__ cnt, const int* __restrict__ off,
    const int* __restrict__ csr, float* __restrict__ out) {
  int wave = threadIdx.x >> 6, lane = threadIdx.x & 63;
  int n = blockIdx.x * 4 + wave;
  if (n >= N_NODES) return;

  int deg = cnt[n], base = off[n];
  float logit = -1e30f;
  if (lane < OUT_CH) {
    float acc = 0.f;
    int k = 0;
    for (; k + 8 <= deg; k += 8) {
      int s0 = csr[base + k + 0], s1 = csr[base + k + 1];
      int s2 = csr[base + k + 2], s3 = csr[base + k + 3];
      int s4 = csr[base + k + 4], s5 = csr[base + k + 5];
      int s6 = csr[base + k + 6], s7 = csr[base + k + 7];
      float v0 = bf2f(hw2[(size_t)s0 * OUT_CH + lane]);
      float v1 = bf2f(hw2[(size_t)s1 * OUT_CH + lane]);
      float v2 = bf2f(hw2[(size_t)s2 * OUT_CH + lane]);
      float v3 = bf2f(hw2[(size_t)s3 * OUT_CH + lane]);
      float v4 = bf2f(hw2[(size_t)s4 * OUT_CH + lane]);
      float v5 = bf2f(hw2[(size_t)s5 * OUT_CH + lane]);
      float v6 = bf2f(hw2[(size_t)s6 * OUT_CH + lane]);
      float v7 = bf2f(hw2[(size_t)s7 * OUT_CH + lane]);
      acc += ((v0 + v1) + (v2 + v3)) + ((v4 + v5) + (v6 + v7));
    }
    if (k < deg) {
#pragma unroll
      for (int i = 0; i < 8; ++i) {
        int kk = k + i;
        int s_ = csr[base + (kk < deg ? kk : k)];
        float v = bf2f(hw2[(size_t)s_ * OUT_CH + lane]);
        if (kk < deg) acc += v;
      }
    }
    logit = acc / fmaxf((float)deg, 1.0f) + self2[(size_t)n * OUT_CH + lane];
  }
  // log_softmax over 40 valid lanes (idle lanes carry identity elements)
  float m = logit;
  for (int o = 32; o; o >>= 1) m = fmaxf(m, __shfl_xor(m, o));
  float e = (lane < OUT_CH) ? expf(logit - m) : 0.f;
  float ssum = e;
  for (int o = 32; o; o >>= 1) ssum += __shfl_xor(ssum, o);
  float lse = logf(ssum);
  if (lane < OUT_CH) out[(size_t)n * OUT_CH + lane] = logit - m - lse;
}

extern "C" void kernel_launch(void* const* d_in, const int* in_sizes, int n_in,
                              void* d_out, int out_size, void* d_ws, size_t ws_size,
                              hipStream_t stream) {
  const float* x   = (const float*)d_in[0];
  const int*   ei  = (const int*)d_in[1];
  const float* W1l = (const float*)d_in[2];
  const float* b1  = (const float*)d_in[3];
  const float* W1r = (const float*)d_in[4];
  const float* W2l = (const float*)d_in[5];
  const float* b2  = (const float*)d_in[6];
  const float* W2r = (const float*)d_in[7];
  float* out = (float*)d_out;

  const int* src = ei;            // edge_index[0]
  const int* dst = ei + N_EDGES;  // edge_index[1]

  // ws layout: f32 arrays first, then bf16, then ints
  float* xwr   = (float*)d_ws;                             // [N*HID] f32
  float* self2 = xwr + (size_t)N_NODES * HID;              // [N*OUT_CH] f32
  float* h1    = self2 + (size_t)N_NODES * OUT_CH;         // [N*HID] f32
  ushort* xwl  = (ushort*)(h1 + (size_t)N_NODES * HID);    // [N*HID] bf16
  ushort* hw2  = xwl + (size_t)N_NODES * HID;              // [N*OUT_CH] bf16
  int* cnt  = (int*)(hw2 + (size_t)N_NODES * OUT_CH);      // [N]
  int* off  = cnt + N_NODES;                               // [N]
  int* cur  = off + N_NODES;                               // [N]
  int* bsum = cur + N_NODES;                               // [256]
  int* csr  = bsum + 256;                                  // [E]

  hipMemsetAsync(cnt, 0, sizeof(int) * N_NODES, stream);

  const int EB = (N_EDGES + 255) / 256;  // 3125
  hist_kernel<<<EB, 256, 0, stream>>>(dst, cnt);
  scan1_kernel<<<NB_SCAN, 256, 0, stream>>>(cnt, off, bsum);
  scan2_kernel<<<1, 256, 0, stream>>>(bsum);
  scan3_kernel<<<NB_SCAN, 256, 0, stream>>>(off, bsum, cur);
  place_kernel<<<EB, 256, 0, stream>>>(src, dst, cur, csr);

  xform1_kernel<<<(N_NODES + 31) / 32, 256, 0, stream>>>(x, W1l, W1r, b1, xwl,
                                                         xwr);
  agg1_kernel<<<(N_NODES + 3) / 4, 256, 0, stream>>>(xwl, xwr, cnt, off, csr,
                                                     h1);
  xform2_kernel<<<(N_NODES + 31) / 32, 256, 0, stream>>>(h1, W2l, W2r, b2, hw2,
                                                         self2);
  agg2_kernel<<<(N_NODES + 3) / 4, 256, 0, stream>>>(hw2, self2, cnt, off, csr,
                                                     out);
}

// Round 11
// 194.982 us; speedup vs baseline: 3.8930x; 1.1192x over previous
//
#include <hip/hip_runtime.h>

#define N_NODES 50000
#define N_EDGES 800000
#define IN_CH 128
#define HID 64
#define OUT_CH 40
#define NB_SCAN 196  // ceil(50000/256)

// ---------------------------------------------------------------------------
// CSR gather, no fp atomics, transform-before-aggregate.
//   xform1 (MFMA): xwl = bf16(x@W1l.T), xwr = x@W1r.T + b1
//     C[h][n] = W[h][:].x[n][:] via mfma_f32_16x16x32_bf16; A=W rows, B=x rows
//     (both row-major [outer][K] -> identical frag reads); LDS tables hold
//     bf16 with byte_in_row ^= (row&15)<<4 swizzle (b128 reads at bank floor).
//   agg1:   h1 = relu(gather_mean(xwl) + xwr)          [paired-edge gather]
//   xform2: hw2 = bf16(h1@W2l.T), self2 = h1@W2r.T + b2
//   agg2:   out = log_softmax(gather_mean(hw2) + self2)
// ---------------------------------------------------------------------------

typedef __attribute__((ext_vector_type(8))) short short8v;
typedef __attribute__((ext_vector_type(4))) float float4v;

__device__ __forceinline__ unsigned f2bf_u(float f) {
  unsigned u = __float_as_uint(f);
  return (u + 0x7FFF + ((u >> 16) & 1)) >> 16;  // RNE
}
__device__ __forceinline__ ushort f2bf(float f) { return (ushort)f2bf_u(f); }
__device__ __forceinline__ float bf2f(ushort u) {
  return __uint_as_float(((unsigned)u) << 16);
}
__device__ __forceinline__ float bflo(unsigned u) {
  return __uint_as_float(u << 16);
}
__device__ __forceinline__ float bfhi(unsigned u) {
  return __uint_as_float(u & 0xFFFF0000u);
}

__global__ __launch_bounds__(256) void hist_kernel(const int* __restrict__ dst,
                                                   int* __restrict__ cnt) {
  int e = blockIdx.x * 256 + threadIdx.x;
  if (e < N_EDGES) atomicAdd(&cnt[dst[e]], 1);
}

__global__ __launch_bounds__(256) void scan1_kernel(const int* __restrict__ cnt,
                                                    int* __restrict__ off,
                                                    int* __restrict__ bsum) {
  __shared__ int s[256];
  int i = blockIdx.x * 256 + threadIdx.x;
  int v = (i < N_NODES) ? cnt[i] : 0;
  s[threadIdx.x] = v;
  __syncthreads();
  for (int o = 1; o < 256; o <<= 1) {
    int t = (threadIdx.x >= o) ? s[threadIdx.x - o] : 0;
    __syncthreads();
    s[threadIdx.x] += t;
    __syncthreads();
  }
  if (i < N_NODES) off[i] = s[threadIdx.x] - v;
  if (threadIdx.x == 255) bsum[blockIdx.x] = s[255];
}

__global__ __launch_bounds__(256) void scan2_kernel(int* __restrict__ bsum) {
  __shared__ int s[256];
  int v = (threadIdx.x < NB_SCAN) ? bsum[threadIdx.x] : 0;
  s[threadIdx.x] = v;
  __syncthreads();
  for (int o = 1; o < 256; o <<= 1) {
    int t = (threadIdx.x >= o) ? s[threadIdx.x - o] : 0;
    __syncthreads();
    s[threadIdx.x] += t;
    __syncthreads();
  }
  if (threadIdx.x < NB_SCAN) bsum[threadIdx.x] = s[threadIdx.x] - v;
}

__global__ __launch_bounds__(256) void scan3_kernel(int* __restrict__ off,
                                                    const int* __restrict__ bsum,
                                                    int* __restrict__ cur) {
  int i = blockIdx.x * 256 + threadIdx.x;
  if (i < N_NODES) {
    int o = off[i] + bsum[blockIdx.x];
    off[i] = o;
    cur[i] = o;
  }
}

__global__ __launch_bounds__(256) void place_kernel(const int* __restrict__ src,
                                                    const int* __restrict__ dst,
                                                    int* __restrict__ cur,
                                                    int* __restrict__ csr) {
  int e = blockIdx.x * 256 + threadIdx.x;
  if (e < N_EDGES) {
    int pos = atomicAdd(&cur[dst[e]], 1);
    csr[pos] = src[e];
  }
}

// pack 8 consecutive floats -> 8 bf16 in a uint4
__device__ __forceinline__ uint4 pack8(const float* p) {
  float4 a = *reinterpret_cast<const float4*>(p);
  float4 b = *reinterpret_cast<const float4*>(p + 4);
  uint4 r;
  r.x = f2bf_u(a.x) | (f2bf_u(a.y) << 16);
  r.y = f2bf_u(a.z) | (f2bf_u(a.w) << 16);
  r.z = f2bf_u(b.x) | (f2bf_u(b.y) << 16);
  r.w = f2bf_u(b.z) | (f2bf_u(b.w) << 16);
  return r;
}

// xwl[n,h] = bf16(x[n,:].W1l[h,:]);  xwr[n,h] = x[n,:].W1r[h,:] + b1[h]
// MFMA: 64 nodes/block (16/wave), A=W1{l,r} [64h x 128c], B=x [64n x 128c].
__global__ __launch_bounds__(256) void xform1_kernel(
    const float* __restrict__ x, const float* __restrict__ W1l,
    const float* __restrict__ W1r, const float* __restrict__ b1,
    ushort* __restrict__ xwl, float* __restrict__ xwr) {
  // bf16 tables, row-major [64][128], swizzle: byte_in_row ^= (row&15)<<4
  __shared__ ushort sWl[64 * 128];  // 16 KB
  __shared__ ushort sWr[64 * 128];  // 16 KB
  __shared__ ushort sx[64 * 128];   // 16 KB
  __shared__ float sb[64];

  int nblk = blockIdx.x * 64;
  // stage x (convert f32->bf16), 1024 16B chunks
  for (int q = threadIdx.x; q < 1024; q += 256) {
    int row = q >> 4, c8 = (q & 15) << 3;
    int boff = row * 256 + (((c8 << 1)) ^ ((row & 15) << 4));
    int n = nblk + row;
    uint4 p = make_uint4(0, 0, 0, 0);
    if (n < N_NODES) p = pack8(x + (size_t)n * IN_CH + c8);
    *reinterpret_cast<uint4*>((char*)sx + boff) = p;
  }
  // stage weights
  for (int q = threadIdx.x; q < 1024; q += 256) {
    int row = q >> 4, c8 = (q & 15) << 3;
    int boff = row * 256 + (((c8 << 1)) ^ ((row & 15) << 4));
    *reinterpret_cast<uint4*>((char*)sWl + boff) =
        pack8(W1l + row * IN_CH + c8);
    *reinterpret_cast<uint4*>((char*)sWr + boff) =
        pack8(W1r + row * IN_CH + c8);
  }
  if (threadIdx.x < 64) sb[threadIdx.x] = b1[threadIdx.x];
  __syncthreads();

  int wave = threadIdx.x >> 6, lane = threadIdx.x & 63;
  int nloc = lane & 15, g = lane >> 4;

  float4v accl[4], accr[4];
#pragma unroll
  for (int m = 0; m < 4; ++m) {
    accl[m] = (float4v){0.f, 0.f, 0.f, 0.f};
    accr[m] = (float4v){0.f, 0.f, 0.f, 0.f};
  }

  int xrow = wave * 16 + nloc;
#pragma unroll
  for (int kt = 0; kt < 4; ++kt) {
    int cb = kt * 64 + g * 16;  // byte col base = (kt*32 + g*8)*2
    short8v bx = *reinterpret_cast<const short8v*>(
        (char*)sx + xrow * 256 + (cb ^ ((xrow & 15) << 4)));
#pragma unroll
    for (int m = 0; m < 4; ++m) {
      int wrow = m * 16 + nloc;
      int so = wrow * 256 + (cb ^ ((wrow & 15) << 4));
      short8v al = *reinterpret_cast<const short8v*>((char*)sWl + so);
      short8v ar = *reinterpret_cast<const short8v*>((char*)sWr + so);
      accl[m] = __builtin_amdgcn_mfma_f32_16x16x32_bf16(al, bx, accl[m], 0, 0, 0);
      accr[m] = __builtin_amdgcn_mfma_f32_16x16x32_bf16(ar, bx, accr[m], 0, 0, 0);
    }
  }

  // C/D layout: col = lane&15 = node, row = g*4 + reg = h (within 16-tile m)
  int n = nblk + wave * 16 + nloc;
  if (n < N_NODES) {
#pragma unroll
    for (int m = 0; m < 4; ++m) {
      int h0 = m * 16 + g * 4;
      uint2 pl;
      pl.x = f2bf_u(accl[m][0]) | (f2bf_u(accl[m][1]) << 16);
      pl.y = f2bf_u(accl[m][2]) | (f2bf_u(accl[m][3]) << 16);
      *reinterpret_cast<uint2*>(xwl + (size_t)n * HID + h0) = pl;
      float4 vr;
      vr.x = accr[m][0] + sb[h0 + 0];
      vr.y = accr[m][1] + sb[h0 + 1];
      vr.z = accr[m][2] + sb[h0 + 2];
      vr.w = accr[m][3] + sb[h0 + 3];
      *reinterpret_cast<float4*>(xwr + (size_t)n * HID + h0) = vr;
    }
  }
}

// h1 = relu(gather_mean(xwl) + xwr) — lean gather, no LDS.
__global__ __launch_bounds__(256) void agg1_kernel(
    const ushort* __restrict__ xwl, const float* __restrict__ xwr,
    const int* __restrict__ cnt, const int* __restrict__ off,
    const int* __restrict__ csr, float* __restrict__ h1) {
  int wave = threadIdx.x >> 6, lane = threadIdx.x & 63;
  int n = blockIdx.x * 4 + wave;
  if (n >= N_NODES) return;

  int deg = cnt[n], base = off[n];
  int half = lane >> 5;  // 0: even edges, 1: odd edges
  int cp = lane & 31;    // channel pair index
  float ax = 0.f, ay = 0.f;

  if (deg > 0) {
    int k = 0;
    for (; k + 8 <= deg; k += 8) {
      int e0 = csr[base + k + 0 + half];
      int e1 = csr[base + k + 2 + half];
      int e2 = csr[base + k + 4 + half];
      int e3 = csr[base + k + 6 + half];
      unsigned u0 =
          *reinterpret_cast<const unsigned*>(xwl + (size_t)e0 * HID + 2 * cp);
      unsigned u1 =
          *reinterpret_cast<const unsigned*>(xwl + (size_t)e1 * HID + 2 * cp);
      unsigned u2 =
          *reinterpret_cast<const unsigned*>(xwl + (size_t)e2 * HID + 2 * cp);
      unsigned u3 =
          *reinterpret_cast<const unsigned*>(xwl + (size_t)e3 * HID + 2 * cp);
      ax += (bflo(u0) + bflo(u1)) + (bflo(u2) + bflo(u3));
      ay += (bfhi(u0) + bfhi(u1)) + (bfhi(u2) + bfhi(u3));
    }
    if (k < deg) {
#pragma unroll
      for (int j = 0; j < 4; ++j) {
        int idx = k + 2 * j + half;
        bool valid = idx < deg;
        int e = csr[base + (valid ? idx : 0)];
        unsigned u =
            *reinterpret_cast<const unsigned*>(xwl + (size_t)e * HID + 2 * cp);
        if (valid) {
          ax += bflo(u);
          ay += bfhi(u);
        }
      }
    }
    ax += __shfl_xor(ax, 32);
    ay += __shfl_xor(ay, 32);
  }

  float inv = 1.0f / fmaxf((float)deg, 1.0f);
  const float2 s =
      *reinterpret_cast<const float2*>(xwr + (size_t)n * HID + 2 * cp);
  float2 h;
  h.x = fmaxf(ax * inv + s.x, 0.f);
  h.y = fmaxf(ay * inv + s.y, 0.f);
  if (half == 0)
    *reinterpret_cast<float2*>(h1 + (size_t)n * HID + 2 * cp) = h;
}

// hw2[n,o] = bf16(h1[n,:].W2l[o,:]);  self2[n,o] = h1[n,:].W2r[o,:] + b2[o]
__global__ __launch_bounds__(256) void xform2_kernel(
    const float* __restrict__ h1, const float* __restrict__ W2l,
    const float* __restrict__ W2r, const float* __restrict__ b2,
    ushort* __restrict__ hw2, float* __restrict__ self2) {
  __shared__ unsigned sWl[HID / 2][OUT_CH + 1];  // 5248 B
  __shared__ unsigned sWr[HID / 2][OUT_CH + 1];  // 5248 B
  __shared__ float sh[32][HID];                  // 8192 B
  for (int i = threadIdx.x; i < OUT_CH * (HID / 2); i += 256) {
    int o = i >> 5, c2 = i & 31;
    float a = W2l[o * HID + 2 * c2], b = W2l[o * HID + 2 * c2 + 1];
    sWl[c2][o] = (unsigned)f2bf(a) | ((unsigned)f2bf(b) << 16);
    float c = W2r[o * HID + 2 * c2], d = W2r[o * HID + 2 * c2 + 1];
    sWr[c2][o] = (unsigned)f2bf(c) | ((unsigned)f2bf(d) << 16);
  }
  int nblk = blockIdx.x * 32;
  for (int s = threadIdx.x; s < 32 * (HID / 4); s += 256) {
    int node = s >> 4, c4 = s & 15;
    int n = nblk + node;
    float4 v = make_float4(0.f, 0.f, 0.f, 0.f);
    if (n < N_NODES)
      v = *reinterpret_cast<const float4*>(h1 + (size_t)n * HID + c4 * 4);
    *reinterpret_cast<float4*>(&sh[node][c4 * 4]) = v;
  }
  __syncthreads();

  int wave = threadIdx.x >> 6, lane = threadIdx.x & 63;
  int n0 = nblk + wave * 8;
  if (n0 >= N_NODES || lane >= OUT_CH) return;
  float bias = b2[lane];

  float accl[8], accr[8];
#pragma unroll
  for (int i = 0; i < 8; ++i) {
    accl[i] = 0.f;
    accr[i] = bias;
  }
  const int nb = wave * 8;
  int nvalid = min(8, N_NODES - n0);
  for (int c = 0; c < HID; c += 4) {
    unsigned ul0 = sWl[(c >> 1) + 0][lane], ul1 = sWl[(c >> 1) + 1][lane];
    unsigned ur0 = sWr[(c >> 1) + 0][lane], ur1 = sWr[(c >> 1) + 1][lane];
    float wl0 = bflo(ul0), wl1 = bfhi(ul0), wl2 = bflo(ul1), wl3 = bfhi(ul1);
    float wr0 = bflo(ur0), wr1 = bfhi(ur0), wr2 = bflo(ur1), wr3 = bfhi(ur1);
#pragma unroll
    for (int i = 0; i < 8; ++i) {
      const float4 hv = *reinterpret_cast<const float4*>(&sh[nb + i][c]);
      accl[i] = fmaf(hv.x, wl0, accl[i]);
      accr[i] = fmaf(hv.x, wr0, accr[i]);
      accl[i] = fmaf(hv.y, wl1, accl[i]);
      accr[i] = fmaf(hv.y, wr1, accr[i]);
      accl[i] = fmaf(hv.z, wl2, accl[i]);
      accr[i] = fmaf(hv.z, wr2, accr[i]);
      accl[i] = fmaf(hv.w, wl3, accl[i]);
      accr[i] = fmaf(hv.w, wr3, accr[i]);
    }
  }
  for (int i = 0; i < nvalid; ++i) {
    hw2[(size_t)(n0 + i) * OUT_CH + lane] = f2bf(accl[i]);
    self2[(size_t)(n0 + i) * OUT_CH + lane] = accr[i];
  }
}

// out = log_softmax(gather_mean(hw2) + self2)  — no LDS, no weights
__global__ __launch_bounds__(256) void agg2_kernel(
    const ushort* __restrict__ hw2, const float* __restrict__ self2,
    const int* __restrict__ cnt, const int* __restrict__ off,
    const int* __restrict__ csr, float* __restrict__ out) {
  int wave = threadIdx.x >> 6, lane = threadIdx.x & 63;
  int n = blockIdx.x * 4 + wave;
  if (n >= N_NODES) return;

  int deg = cnt[n], base = off[n];
  float logit = -1e30f;
  if (lane < OUT_CH) {
    float acc = 0.f;
    int k = 0;
    for (; k + 8 <= deg; k += 8) {
      int s0 = csr[base + k + 0], s1 = csr[base + k + 1];
      int s2 = csr[base + k + 2], s3 = csr[base + k + 3];
      int s4 = csr[base + k + 4], s5 = csr[base + k + 5];
      int s6 = csr[base + k + 6], s7 = csr[base + k + 7];
      float v0 = bf2f(hw2[(size_t)s0 * OUT_CH + lane]);
      float v1 = bf2f(hw2[(size_t)s1 * OUT_CH + lane]);
      float v2 = bf2f(hw2[(size_t)s2 * OUT_CH + lane]);
      float v3 = bf2f(hw2[(size_t)s3 * OUT_CH + lane]);
      float v4 = bf2f(hw2[(size_t)s4 * OUT_CH + lane]);
      float v5 = bf2f(hw2[(size_t)s5 * OUT_CH + lane]);
      float v6 = bf2f(hw2[(size_t)s6 * OUT_CH + lane]);
      float v7 = bf2f(hw2[(size_t)s7 * OUT_CH + lane]);
      acc += ((v0 + v1) + (v2 + v3)) + ((v4 + v5) + (v6 + v7));
    }
    if (k < deg) {
#pragma unroll
      for (int i = 0; i < 8; ++i) {
        int kk = k + i;
        int s_ = csr[base + (kk < deg ? kk : k)];
        float v = bf2f(hw2[(size_t)s_ * OUT_CH + lane]);
        if (kk < deg) acc += v;
      }
    }
    logit = acc / fmaxf((float)deg, 1.0f) + self2[(size_t)n * OUT_CH + lane];
  }
  float m = logit;
  for (int o = 32; o; o >>= 1) m = fmaxf(m, __shfl_xor(m, o));
  float e = (lane < OUT_CH) ? expf(logit - m) : 0.f;
  float ssum = e;
  for (int o = 32; o; o >>= 1) ssum += __shfl_xor(ssum, o);
  float lse = logf(ssum);
  if (lane < OUT_CH) out[(size_t)n * OUT_CH + lane] = logit - m - lse;
}

extern "C" void kernel_launch(void* const* d_in, const int* in_sizes, int n_in,
                              void* d_out, int out_size, void* d_ws, size_t ws_size,
                              hipStream_t stream) {
  const float* x   = (const float*)d_in[0];
  const int*   ei  = (const int*)d_in[1];
  const float* W1l = (const float*)d_in[2];
  const float* b1  = (const float*)d_in[3];
  const float* W1r = (const float*)d_in[4];
  const float* W2l = (const float*)d_in[5];
  const float* b2  = (const float*)d_in[6];
  const float* W2r = (const float*)d_in[7];
  float* out = (float*)d_out;

  const int* src = ei;            // edge_index[0]
  const int* dst = ei + N_EDGES;  // edge_index[1]

  // ws layout: f32 arrays first, then bf16, then ints
  float* xwr   = (float*)d_ws;                             // [N*HID] f32
  float* self2 = xwr + (size_t)N_NODES * HID;              // [N*OUT_CH] f32
  float* h1    = self2 + (size_t)N_NODES * OUT_CH;         // [N*HID] f32
  ushort* xwl  = (ushort*)(h1 + (size_t)N_NODES * HID);    // [N*HID] bf16
  ushort* hw2  = xwl + (size_t)N_NODES * HID;              // [N*OUT_CH] bf16
  int* cnt  = (int*)(hw2 + (size_t)N_NODES * OUT_CH);      // [N]
  int* off  = cnt + N_NODES;                               // [N]
  int* cur  = off + N_NODES;                               // [N]
  int* bsum = cur + N_NODES;                               // [256]
  int* csr  = bsum + 256;                                  // [E]

  hipMemsetAsync(cnt, 0, sizeof(int) * N_NODES, stream);

  const int EB = (N_EDGES + 255) / 256;  // 3125
  hist_kernel<<<EB, 256, 0, stream>>>(dst, cnt);
  scan1_kernel<<<NB_SCAN, 256, 0, stream>>>(cnt, off, bsum);
  scan2_kernel<<<1, 256, 0, stream>>>(bsum);
  scan3_kernel<<<NB_SCAN, 256, 0, stream>>>(off, bsum, cur);
  place_kernel<<<EB, 256, 0, stream>>>(src, dst, cur, csr);

  xform1_kernel<<<(N_NODES + 63) / 64, 256, 0, stream>>>(x, W1l, W1r, b1, xwl,
                                                         xwr);
  agg1_kernel<<<(N_NODES + 3) / 4, 256, 0, stream>>>(xwl, xwr, cnt, off, csr,
                                                     h1);
  xform2_kernel<<<(N_NODES + 31) / 32, 256, 0, stream>>>(h1, W2l, W2r, b2, hw2,
                                                         self2);
  agg2_kernel<<<(N_NODES + 3) / 4, 256, 0, stream>>>(hw2, self2, cnt, off, csr,
                                                     out);
}